// Round 1
// baseline (4765.913 us; speedup 1.0000x reference)
//
#include <hip/hip_runtime.h>

typedef __attribute__((ext_vector_type(8))) short s16x8;
typedef __attribute__((ext_vector_type(4))) float f32x4;

#define B_ 32
#define D_ 256
#define K_ 128
#define DIM_ 512
#define HEADS_ 8
#define HD_ 64
#define S_ 256
#define TOK_ (B_*D_)          // 8192 rows

__device__ __forceinline__ unsigned short f2bf(float f) {
    union { float f; unsigned int u; } v; v.f = f;
    unsigned int r = v.u + 0x7fffu + ((v.u >> 16) & 1u);
    return (unsigned short)(r >> 16);
}
__device__ __forceinline__ float bf2f(unsigned short u) {
    union { unsigned int u; float f; } v; v.u = ((unsigned int)u) << 16;
    return v.f;
}

// ---------------------------------------------------------------------------
// Generic batched GEMM: C[m][n] = sum_k A[m][k] * Bw[n][k]
// A: bf16 (ushort) row-major lda=K.  Bw: f32 or bf16 row-major ldb=K.
// EPI: 0 store f32; 1 f32 +=; 2 relu^2 -> bf16; 3 +bias -> f32; 4 store bf16
// C offset per batch z: (z/zdiv)*sC1 + (z%zdiv)*sC2
// ---------------------------------------------------------------------------
template<int BM, int BN, int WM, int WN, bool BF16B, int EPI>
__global__ __launch_bounds__(WM*WN*64)
void gemm_k(const unsigned short* __restrict__ A, const void* __restrict__ Bv,
            void* __restrict__ Cv, const float* __restrict__ bias,
            int K, int ldc, long sA, long sB, int zdiv, long sC1, long sC2)
{
    constexpr int THREADS = WM*WN*64;
    constexpr int FM = BM/(WM*16), FN = BN/(WN*16);
    constexpr int KP = 40;   // padded K-stride (bf16 elems): 80B, conflict-free-ish
    __shared__ unsigned short As[BM*KP];
    __shared__ unsigned short Bs[BN*KP];

    const int tid = threadIdx.x;
    const int z = blockIdx.z;
    const long m0 = (long)blockIdx.y * BM;
    const long n0 = (long)blockIdx.x * BN;
    const unsigned short* Ab = A + z*sA + m0*K;
    const long coff = (long)(z/zdiv)*sC1 + (long)(z%zdiv)*sC2;

    const int w = tid >> 6, lane = tid & 63;
    const int wm = w / WN, wn = w % WN;
    const int lr = lane & 15, lq = lane >> 4;

    f32x4 acc[FM][FN] = {};

    for (int k0 = 0; k0 < K; k0 += 32) {
        // stage A (bf16)
        #pragma unroll
        for (int c = 0; c < BM*32/(THREADS*8); ++c) {
            int lin = c*THREADS + tid;
            int row = lin >> 2, ko = (lin & 3) * 8;
            *(int4*)&As[row*KP + ko] = *(const int4*)&Ab[(long)row*K + k0 + ko];
        }
        // stage B
        if constexpr (BF16B) {
            const unsigned short* Bb = (const unsigned short*)Bv + z*sB + n0*K;
            #pragma unroll
            for (int c = 0; c < BN*32/(THREADS*8); ++c) {
                int lin = c*THREADS + tid;
                int row = lin >> 2, ko = (lin & 3) * 8;
                *(int4*)&Bs[row*KP + ko] = *(const int4*)&Bb[(long)row*K + k0 + ko];
            }
        } else {
            const float* Bb = (const float*)Bv + z*sB + n0*K;
            #pragma unroll
            for (int c = 0; c < BN*32/(THREADS*4); ++c) {
                int lin = c*THREADS + tid;
                int row = lin >> 3, ko = (lin & 7) * 4;
                float4 v = *(const float4*)&Bb[(long)row*K + k0 + ko];
                ushort4 o;
                o.x = f2bf(v.x); o.y = f2bf(v.y); o.z = f2bf(v.z); o.w = f2bf(v.w);
                *(ushort4*)&Bs[row*KP + ko] = o;
            }
        }
        __syncthreads();
        s16x8 af[FM], bfr[FN];
        #pragma unroll
        for (int fm = 0; fm < FM; ++fm)
            af[fm] = *(const s16x8*)&As[(wm*FM*16 + fm*16 + lr)*KP + lq*8];
        #pragma unroll
        for (int fn = 0; fn < FN; ++fn)
            bfr[fn] = *(const s16x8*)&Bs[(wn*FN*16 + fn*16 + lr)*KP + lq*8];
        #pragma unroll
        for (int fm = 0; fm < FM; ++fm)
            #pragma unroll
            for (int fn = 0; fn < FN; ++fn)
                acc[fm][fn] = __builtin_amdgcn_mfma_f32_16x16x32_bf16(
                    af[fm], bfr[fn], acc[fm][fn], 0, 0, 0);
        __syncthreads();
    }

    #pragma unroll
    for (int fm = 0; fm < FM; ++fm) {
        long mrow = m0 + wm*FM*16 + fm*16 + lq*4;
        #pragma unroll
        for (int fn = 0; fn < FN; ++fn) {
            long ncol = n0 + wn*FN*16 + fn*16 + lr;
            #pragma unroll
            for (int r = 0; r < 4; ++r) {
                long ci = coff + (mrow + r)*ldc + ncol;
                float v = acc[fm][fn][r];
                if constexpr (EPI == 0) ((float*)Cv)[ci] = v;
                else if constexpr (EPI == 1) ((float*)Cv)[ci] += v;
                else if constexpr (EPI == 2) { float t = fmaxf(v, 0.f); ((unsigned short*)Cv)[ci] = f2bf(t*t); }
                else if constexpr (EPI == 3) ((float*)Cv)[ci] = v + bias[ncol];
                else ((unsigned short*)Cv)[ci] = f2bf(v);
            }
        }
    }
}

// ---------------------------------------------------------------------------
// Fused scores + row softmax.  grid (4 qtiles, 256 bh).  Writes P bf16.
// Q is pre-scaled by 1/8 in qk_rope.
// ---------------------------------------------------------------------------
__global__ __launch_bounds__(256)
void attn_scores(const unsigned short* __restrict__ Qn,
                 const unsigned short* __restrict__ Kn,
                 unsigned short* __restrict__ P)
{
    constexpr int KP = 72;
    __shared__ unsigned short Qs[64*KP];
    __shared__ unsigned short Ks[256*KP];
    const int tid = threadIdx.x;
    const int bh = blockIdx.y;
    const int m0 = blockIdx.x * 64;
    const unsigned short* Qb = Qn + (long)bh*S_*HD_ + (long)m0*HD_;
    const unsigned short* Kb = Kn + (long)bh*S_*HD_;

    #pragma unroll
    for (int c = 0; c < 2; ++c) { int lin = c*256 + tid; int row = lin>>3, ko = (lin&7)*8;
        *(int4*)&Qs[row*KP + ko] = *(const int4*)&Qb[row*64 + ko]; }
    #pragma unroll
    for (int c = 0; c < 8; ++c) { int lin = c*256 + tid; int row = lin>>3, ko = (lin&7)*8;
        *(int4*)&Ks[row*KP + ko] = *(const int4*)&Kb[row*64 + ko]; }
    __syncthreads();

    const int w = tid >> 6, lane = tid & 63, lr = lane & 15, lq = lane >> 4;
    s16x8 a0 = *(const s16x8*)&Qs[(w*16 + lr)*KP + lq*8];
    s16x8 a1 = *(const s16x8*)&Qs[(w*16 + lr)*KP + 32 + lq*8];
    f32x4 acc[16];
    #pragma unroll
    for (int fn = 0; fn < 16; ++fn) {
        s16x8 b0 = *(const s16x8*)&Ks[(fn*16 + lr)*KP + lq*8];
        s16x8 b1 = *(const s16x8*)&Ks[(fn*16 + lr)*KP + 32 + lq*8];
        f32x4 c = {0.f, 0.f, 0.f, 0.f};
        c = __builtin_amdgcn_mfma_f32_16x16x32_bf16(a0, b0, c, 0, 0, 0);
        c = __builtin_amdgcn_mfma_f32_16x16x32_bf16(a1, b1, c, 0, 0, 0);
        acc[fn] = c;
    }
    #pragma unroll
    for (int r = 0; r < 4; ++r) {
        float mx = -1e30f;
        #pragma unroll
        for (int fn = 0; fn < 16; ++fn) mx = fmaxf(mx, acc[fn][r]);
        #pragma unroll
        for (int off = 1; off < 16; off <<= 1) mx = fmaxf(mx, __shfl_xor(mx, off, 64));
        float e[16], sum = 0.f;
        #pragma unroll
        for (int fn = 0; fn < 16; ++fn) { e[fn] = __expf(acc[fn][r] - mx); sum += e[fn]; }
        #pragma unroll
        for (int off = 1; off < 16; off <<= 1) sum += __shfl_xor(sum, off, 64);
        float inv = 1.f / sum;
        long rowg = m0 + w*16 + lq*4 + r;
        #pragma unroll
        for (int fn = 0; fn < 16; ++fn)
            P[(long)bh*65536 + rowg*256 + fn*16 + lr] = f2bf(e[fn]*inv);
    }
}

// rms over 512 cols, f32 in -> bf16 out. 4 rows/block (1 per wave).
__global__ __launch_bounds__(256)
void rms_rows(const float* __restrict__ in, unsigned short* __restrict__ out)
{
    int row = blockIdx.x*4 + (threadIdx.x >> 6);
    int lane = threadIdx.x & 63;
    const float* r = in + (long)row*DIM_;
    float4 v0 = *(const float4*)&r[lane*4];
    float4 v1 = *(const float4*)&r[256 + lane*4];
    float ss = v0.x*v0.x + v0.y*v0.y + v0.z*v0.z + v0.w*v0.w
             + v1.x*v1.x + v1.y*v1.y + v1.z*v1.z + v1.w*v1.w;
    #pragma unroll
    for (int off = 1; off < 64; off <<= 1) ss += __shfl_xor(ss, off, 64);
    float sc = rsqrtf(ss * (1.f/512.f) + 1e-6f);
    ushort4 o0, o1;
    o0.x = f2bf(v0.x*sc); o0.y = f2bf(v0.y*sc); o0.z = f2bf(v0.z*sc); o0.w = f2bf(v0.w*sc);
    o1.x = f2bf(v1.x*sc); o1.y = f2bf(v1.y*sc); o1.z = f2bf(v1.z*sc); o1.w = f2bf(v1.w*sc);
    *(ushort4*)&out[(long)row*DIM_ + lane*4] = o0;
    *(ushort4*)&out[(long)row*DIM_ + 256 + lane*4] = o1;
}

// per-token QK rms-norm + rope (+1/8 score scale on Q), V transpose. grid 8192.
__global__ __launch_bounds__(256)
void qk_rope(const float* __restrict__ qkv, const float* __restrict__ cost,
             const float* __restrict__ sint, unsigned short* __restrict__ Qn,
             unsigned short* __restrict__ Kn, unsigned short* __restrict__ VT)
{
    int token = blockIdx.x;            // b*S + s
    int s = token & 255, b = token >> 8;
    int t = threadIdx.x;
    int hh = t >> 5, j = t & 31;
    const float* row = qkv + (long)token*1536;
    float q0 = row[hh*64 + 2*j],        q1 = row[hh*64 + 2*j + 1];
    float k0 = row[512 + hh*64 + 2*j],  k1 = row[512 + hh*64 + 2*j + 1];
    float qs = q0*q0 + q1*q1, ks = k0*k0 + k1*k1;
    #pragma unroll
    for (int off = 1; off < 32; off <<= 1) { qs += __shfl_xor(qs, off, 64); ks += __shfl_xor(ks, off, 64); }
    float qsc = rsqrtf(qs*(1.f/64.f) + 1e-6f) * 0.125f;
    float ksc = rsqrtf(ks*(1.f/64.f) + 1e-6f);
    float c = cost[s*32 + j], sn = sint[s*32 + j];
    q0 *= qsc; q1 *= qsc; k0 *= ksc; k1 *= ksc;
    float qo0 = q0*c - q1*sn, qo1 = q0*sn + q1*c;
    float ko0 = k0*c - k1*sn, ko1 = k0*sn + k1*c;
    int bh = b*HEADS_ + hh;
    long base = (long)bh*S_*HD_ + (long)s*HD_ + 2*j;
    ushort2 qw; qw.x = f2bf(qo0); qw.y = f2bf(qo1);
    ushort2 kw; kw.x = f2bf(ko0); kw.y = f2bf(ko1);
    *(ushort2*)&Qn[base] = qw;
    *(ushort2*)&Kn[base] = kw;
    float v0 = row[1024 + hh*64 + 2*j], v1 = row[1024 + hh*64 + 2*j + 1];
    VT[(long)bh*S_*HD_ + (long)(2*j)*S_ + s]     = f2bf(v0);
    VT[(long)bh*S_*HD_ + (long)(2*j+1)*S_ + s]   = f2bf(v1);
}

// h[b,d,:] = mask ? embed_W[:, idx] : 0  (+ pos_embed[d,:]).  grid 8192.
__global__ __launch_bounds__(256)
void embed_k(float* __restrict__ h, const int* __restrict__ xidx,
             const float* __restrict__ eW, const float* __restrict__ pos, int par)
{
    int row = blockIdx.x;
    int d = row & 255;
    int mask = (((d & 1) == 0) == (par != 0)) ? 1 : 0;
    int idx = xidx[row];
    int t = threadIdx.x;
    #pragma unroll
    for (int c0 = 0; c0 < 2; ++c0) {
        int c = c0*256 + t;
        float v = pos[d*DIM_ + c];
        if (mask) v += eW[(long)c*K_ + idx];
        h[(long)row*DIM_ + c] = v;
    }
}

__global__ __launch_bounds__(256)
void skip_scale(float* __restrict__ h, const float* __restrict__ alpha, int n4)
{
    float s = 1.f + 1.f/(1.f + __expf(-alpha[0]));
    for (long i = blockIdx.x*256 + threadIdx.x; i < n4; i += (long)gridDim.x*256) {
        float4 v = ((float4*)h)[i];
        v.x *= s; v.y *= s; v.z *= s; v.w *= s;
        ((float4*)h)[i] = v;
    }
}

__global__ __launch_bounds__(256)
void skip_add(float* __restrict__ h, const float* __restrict__ skip,
              const float* __restrict__ alpha, int n4)
{
    float s = 1.f/(1.f + __expf(-alpha[0]));
    for (long i = blockIdx.x*256 + threadIdx.x; i < n4; i += (long)gridDim.x*256) {
        float4 v = ((float4*)h)[i];
        float4 u = ((const float4*)skip)[i];
        v.x += s*u.x; v.y += s*u.y; v.z += s*u.z; v.w += s*u.w;
        ((float4*)h)[i] = v;
    }
}

// argmax over 128 logits; update x_idx where mask==0.  4 rows/block.
__global__ __launch_bounds__(256)
void argmax_update(const float* __restrict__ logits, int* __restrict__ xidx, int par)
{
    int row = blockIdx.x*4 + (threadIdx.x >> 6);
    int d = row & 255;
    int maskbit = (((d & 1) == 0) == (par != 0)) ? 1 : 0;
    if (maskbit) return;
    int lane = threadIdx.x & 63;
    float v0 = logits[(long)row*K_ + lane], v1 = logits[(long)row*K_ + 64 + lane];
    float bv; int bi;
    if (v1 > v0) { bv = v1; bi = lane + 64; } else { bv = v0; bi = lane; }
    #pragma unroll
    for (int off = 1; off < 64; off <<= 1) {
        float ov = __shfl_xor(bv, off, 64);
        int oi = __shfl_xor(bi, off, 64);
        if (ov > bv || (ov == bv && oi < bi)) { bv = ov; bi = oi; }
    }
    if (lane == 0) xidx[row] = (xidx[row] - bi) & (K_ - 1);
}

__global__ __launch_bounds__(256)
void setup_cossin(float* __restrict__ cost, float* __restrict__ sint)
{
    for (int idx = blockIdx.x*256 + threadIdx.x; idx < D_*32; idx += gridDim.x*256) {
        int d = idx >> 5, j = idx & 31;
        float inv = powf(10000.f, -(float)j/32.f);
        float ang = (float)d * inv;
        cost[idx] = cosf(ang);
        sint[idx] = sinf(ang);
    }
}

__global__ __launch_bounds__(256)
void setup_lse(const float* __restrict__ bl, float* __restrict__ lse)
{
    int row = blockIdx.x*4 + (threadIdx.x >> 6);
    int lane = threadIdx.x & 63;
    float v0 = bl[(long)row*K_ + lane], v1 = bl[(long)row*K_ + 64 + lane];
    float mx = fmaxf(v0, v1);
    #pragma unroll
    for (int off = 1; off < 64; off <<= 1) mx = fmaxf(mx, __shfl_xor(mx, off, 64));
    float s = __expf(v0 - mx) + __expf(v1 - mx);
    #pragma unroll
    for (int off = 1; off < 64; off <<= 1) s += __shfl_xor(s, off, 64);
    if (lane == 0) lse[row] = logf(s) + mx;
}

__global__ __launch_bounds__(256)
void init_xidx(const int* __restrict__ y, int* __restrict__ xidx)
{
    int i = blockIdx.x*256 + threadIdx.x;
    if (i < TOK_) xidx[i] = y[i];
}

__global__ __launch_bounds__(256)
void final_out(const float* __restrict__ bl, const float* __restrict__ lse,
               const int* __restrict__ xidx, float* __restrict__ out)
{
    int b = blockIdx.x;
    int d = threadIdx.x;            // D_ == 256 == blockDim
    float v = bl[(long)d*K_ + xidx[b*D_ + d]] - lse[d];
    #pragma unroll
    for (int off = 1; off < 64; off <<= 1) v += __shfl_xor(v, off, 64);
    __shared__ float wsum[4];
    if ((threadIdx.x & 63) == 0) wsum[threadIdx.x >> 6] = v;
    __syncthreads();
    if (threadIdx.x == 0) out[b] = wsum[0] + wsum[1] + wsum[2] + wsum[3];
}

// ---------------------------------------------------------------------------
extern "C" void kernel_launch(void* const* d_in, const int* in_sizes, int n_in,
                              void* d_out, int out_size, void* d_ws, size_t ws_size,
                              hipStream_t stream)
{
    const int*   y        = (const int*)  d_in[0];
    const float* base_lg  = (const float*)d_in[1];
    const float* embed_W  = (const float*)d_in[2];
    const float* pos_emb  = (const float*)d_in[3];
    const float* qkv_W    = (const float*)d_in[4];
    const float* out_W    = (const float*)d_in[5];
    const float* up_W     = (const float*)d_in[6];
    const float* down_W   = (const float*)d_in[7];
    const float* skip_al  = (const float*)d_in[8];
    const float* head_W   = (const float*)d_in[9];
    const float* head_b   = (const float*)d_in[10];
    float* out = (float*)d_out;

    char* w = (char*)d_ws;
    auto alloc = [&](size_t bytes) { char* p = w; w += (bytes + 255) & ~(size_t)255; return p; };
    float* cost   = (float*)alloc(D_*32*4);
    float* sint   = (float*)alloc(D_*32*4);
    float* lse    = (float*)alloc(D_*4);
    int*   xidx   = (int*)  alloc(TOK_*4);
    float* h      = (float*)alloc((size_t)TOK_*DIM_*4);
    float* skip   = (float*)alloc((size_t)TOK_*DIM_*4);
    unsigned short* xa = (unsigned short*)alloc((size_t)TOK_*DIM_*2);
    float* U      = (float*)alloc((size_t)TOK_*1536*4);          // qkv f32
    unsigned short* P  = (unsigned short*)alloc((size_t)256*S_*S_*2); // softmax P / up-out
    unsigned short* Qn = (unsigned short*)alloc((size_t)256*S_*HD_*2);
    unsigned short* Kn = (unsigned short*)alloc((size_t)256*S_*HD_*2);
    unsigned short* VT = (unsigned short*)alloc((size_t)256*S_*HD_*2);
    unsigned short* O  = (unsigned short*)alloc((size_t)TOK_*DIM_*2);
    float* logits = (float*)alloc((size_t)TOK_*K_*4);

    setup_cossin<<<32, 256, 0, stream>>>(cost, sint);
    setup_lse<<<D_/4, 256, 0, stream>>>(base_lg, lse);
    init_xidx<<<TOK_/256, 256, 0, stream>>>(y, xidx);

    const int n4 = TOK_*DIM_/4;

    for (int flow = 3; flow >= 0; --flow) {
        int par = (flow % 2 == 0) ? 1 : 0;
        embed_k<<<TOK_, 256, 0, stream>>>(h, xidx,
            embed_W + (long)flow*DIM_*K_, pos_emb + (long)flow*D_*DIM_, par);

        for (int layer = 0; layer < 4; ++layer) {
            long wi = (long)(flow*4 + layer);
            const float* qkvW = qkv_W + wi*1536*512;
            const float* oW   = out_W + wi*512*512;
            const float* upW  = up_W  + wi*2048*512;
            const float* dnW  = down_W+ wi*512*2048;

            if (layer == 2) skip_scale<<<1024, 256, 0, stream>>>(h, skip_al + flow*2 + 0, n4);
            if (layer == 3) skip_add  <<<1024, 256, 0, stream>>>(h, skip, skip_al + flow*2 + 1, n4);

            // ---- attention ----
            rms_rows<<<TOK_/4, 256, 0, stream>>>(h, xa);
            gemm_k<128,128,2,2,false,0><<<dim3(12,64,1), 256, 0, stream>>>(
                xa, qkvW, U, nullptr, 512, 1536, 0, 0, 1, 0, 0);
            qk_rope<<<TOK_, 256, 0, stream>>>(U, cost, sint, Qn, Kn, VT);
            attn_scores<<<dim3(4,256), 256, 0, stream>>>(Qn, Kn, P);
            gemm_k<128,64,4,1,true,4><<<dim3(1,2,256), 256, 0, stream>>>(
                P, VT, O, nullptr, 256, 512, 65536, 16384, 8, (long)S_*DIM_, 64);
            gemm_k<128,128,2,2,false,1><<<dim3(4,64,1), 256, 0, stream>>>(
                O, oW, h, nullptr, 512, 512, 0, 0, 1, 0, 0);

            // ---- mlp ----
            rms_rows<<<TOK_/4, 256, 0, stream>>>(h, xa);
            gemm_k<128,128,2,2,false,2><<<dim3(16,64,1), 256, 0, stream>>>(
                xa, upW, P, nullptr, 512, 2048, 0, 0, 1, 0, 0);
            gemm_k<128,128,2,2,false,1><<<dim3(4,64,1), 256, 0, stream>>>(
                P, dnW, h, nullptr, 2048, 512, 0, 0, 1, 0, 0);

            if (layer == 0)
                hipMemcpyAsync(skip, h, (size_t)TOK_*DIM_*4, hipMemcpyDeviceToDevice, stream);
        }

        rms_rows<<<TOK_/4, 256, 0, stream>>>(h, xa);
        gemm_k<128,128,2,2,false,3><<<dim3(1,64,1), 256, 0, stream>>>(
            xa, head_W + (long)flow*K_*DIM_, logits, head_b + flow*K_,
            512, 128, 0, 0, 1, 0, 0);
        argmax_update<<<TOK_/4, 256, 0, stream>>>(logits, xidx, par);
    }

    final_out<<<B_, 256, 0, stream>>>(base_lg, lse, xidx, out);
}

// Round 3
// 3887.325 us; speedup vs baseline: 1.2260x; 1.2260x over previous
//
#include <hip/hip_runtime.h>

typedef __attribute__((ext_vector_type(8))) short s16x8;
typedef __attribute__((ext_vector_type(4))) float f32x4;

#define B_ 32
#define D_ 256
#define K_ 128
#define DIM_ 512
#define HEADS_ 8
#define HD_ 64
#define S_ 256
#define TOK_ (B_*D_)          // 8192 rows

__device__ __forceinline__ unsigned short f2bf(float f) {
    union { float f; unsigned int u; } v; v.f = f;
    unsigned int r = v.u + 0x7fffu + ((v.u >> 16) & 1u);
    return (unsigned short)(r >> 16);
}

typedef const __attribute__((address_space(1))) unsigned int* gp1_t;
typedef __attribute__((address_space(3))) unsigned int* lp3_t;
__device__ __forceinline__ void gload16(const void* g, void* l) {
    __builtin_amdgcn_global_load_lds((gp1_t)g, (lp3_t)l, 16, 0, 0);
}

// ---------------------------------------------------------------------------
// bf16 GEMM, global_load_lds staging, linear LDS, BK=32, m97 structure.
// C[m][n] = sum_k A[m][k]*Bw[n][k];  A,Bw bf16 row-major (lda=ldb=K).
// EPI: 0 store f32; 1 f32 +=; 2 relu^2->bf16; 3 +bias->f32; 4 store bf16
// batch z: A += z*sA, B += z*sB, C += (z/zdiv)*sC1 + (z%zdiv)*sC2
// ---------------------------------------------------------------------------
template<int BM, int BN, int EPI, bool SWZ>
__global__ __launch_bounds__(256)
void gemm_lds(const unsigned short* __restrict__ A, const unsigned short* __restrict__ Bw,
              void* __restrict__ Cv, const float* __restrict__ bias,
              int K, int ldc, long sA, long sB, int zdiv, long sC1, long sC2)
{
    constexpr int THREADS = 256;
    constexpr int FM = BM/32, FN = BN/32;   // 2 waves per dim (WM=WN=2)
    __shared__ unsigned short As[BM*32];
    __shared__ unsigned short Bs[BN*32];

    const int tid = threadIdx.x;
    const int z = blockIdx.z;
    int bx = blockIdx.x, by = blockIdx.y;
    if constexpr (SWZ) {
        int gx = gridDim.x;
        int nwg = gx * gridDim.y;
        int flat = by*gx + bx;
        int cpx = nwg >> 3;
        int swz = (flat & 7)*cpx + (flat >> 3);
        by = swz / gx; bx = swz - by*gx;
    }
    const long m0 = (long)by * BM;
    const long n0 = (long)bx * BN;
    const unsigned short* Ab = A + z*sA + m0*K;
    const unsigned short* Bb = Bw + z*sB + n0*K;
    const long coff = (long)(z/zdiv)*sC1 + (long)(z%zdiv)*sC2;

    const int w = tid >> 6, lane = tid & 63;
    const int wm = w >> 1, wn = w & 1;
    const int lr = lane & 15, lq = lane >> 4;

    f32x4 acc[FM][FN] = {};

    for (int k0 = 0; k0 < K; k0 += 32) {
        #pragma unroll
        for (int p = 0; p < BM*4/THREADS; ++p) {
            int idx = p*THREADS + tid;
            int r = idx >> 2, s = idx & 3;
            gload16(&Ab[(long)r*K + k0 + s*8], &As[idx*8]);
        }
        #pragma unroll
        for (int p = 0; p < BN*4/THREADS; ++p) {
            int idx = p*THREADS + tid;
            int r = idx >> 2, s = idx & 3;
            gload16(&Bb[(long)r*K + k0 + s*8], &Bs[idx*8]);
        }
        __syncthreads();
        s16x8 af[FM], bfr[FN];
        #pragma unroll
        for (int fm = 0; fm < FM; ++fm)
            af[fm] = *(const s16x8*)&As[(wm*FM*16 + fm*16 + lr)*32 + lq*8];
        #pragma unroll
        for (int fn = 0; fn < FN; ++fn)
            bfr[fn] = *(const s16x8*)&Bs[(wn*FN*16 + fn*16 + lr)*32 + lq*8];
        #pragma unroll
        for (int fm = 0; fm < FM; ++fm)
            #pragma unroll
            for (int fn = 0; fn < FN; ++fn)
                acc[fm][fn] = __builtin_amdgcn_mfma_f32_16x16x32_bf16(
                    af[fm], bfr[fn], acc[fm][fn], 0, 0, 0);
        __syncthreads();
    }

    #pragma unroll
    for (int fm = 0; fm < FM; ++fm) {
        long mrow = m0 + wm*FM*16 + fm*16 + lq*4;
        #pragma unroll
        for (int fn = 0; fn < FN; ++fn) {
            long ncol = n0 + wn*FN*16 + fn*16 + lr;
            #pragma unroll
            for (int r = 0; r < 4; ++r) {
                long ci = coff + (mrow + r)*ldc + ncol;
                float v = acc[fm][fn][r];
                if constexpr (EPI == 0) ((float*)Cv)[ci] = v;
                else if constexpr (EPI == 1) ((float*)Cv)[ci] += v;
                else if constexpr (EPI == 2) { float t = fmaxf(v, 0.f); ((unsigned short*)Cv)[ci] = f2bf(t*t); }
                else if constexpr (EPI == 3) ((float*)Cv)[ci] = v + bias[ncol];
                else ((unsigned short*)Cv)[ci] = f2bf(v);
            }
        }
    }
}

// f32 -> bf16 weight conversion (vectorized, grid-stride)
__global__ __launch_bounds__(256)
void conv_bf16(const float* __restrict__ in, unsigned short* __restrict__ out, int n4)
{
    for (int i = blockIdx.x*256 + threadIdx.x; i < n4; i += gridDim.x*256) {
        float4 v = ((const float4*)in)[i];
        ushort4 o; o.x = f2bf(v.x); o.y = f2bf(v.y); o.z = f2bf(v.z); o.w = f2bf(v.w);
        ((ushort4*)out)[i] = o;
    }
}

// ---------------------------------------------------------------------------
// Fused scores + row softmax.  grid (4 qtiles, 256 bh).  Writes P bf16.
// Q is pre-scaled by 1/8 in qk_rope.
// ---------------------------------------------------------------------------
__global__ __launch_bounds__(256)
void attn_scores(const unsigned short* __restrict__ Qn,
                 const unsigned short* __restrict__ Kn,
                 unsigned short* __restrict__ P)
{
    constexpr int KP = 72;
    __shared__ unsigned short Qs[64*KP];
    __shared__ unsigned short Ks[256*KP];
    const int tid = threadIdx.x;
    const int bh = blockIdx.y;
    const int m0 = blockIdx.x * 64;
    const unsigned short* Qb = Qn + (long)bh*S_*HD_ + (long)m0*HD_;
    const unsigned short* Kb = Kn + (long)bh*S_*HD_;

    #pragma unroll
    for (int c = 0; c < 2; ++c) { int lin = c*256 + tid; int row = lin>>3, ko = (lin&7)*8;
        *(int4*)&Qs[row*KP + ko] = *(const int4*)&Qb[row*64 + ko]; }
    #pragma unroll
    for (int c = 0; c < 8; ++c) { int lin = c*256 + tid; int row = lin>>3, ko = (lin&7)*8;
        *(int4*)&Ks[row*KP + ko] = *(const int4*)&Kb[row*64 + ko]; }
    __syncthreads();

    const int w = tid >> 6, lane = tid & 63, lr = lane & 15, lq = lane >> 4;
    s16x8 a0 = *(const s16x8*)&Qs[(w*16 + lr)*KP + lq*8];
    s16x8 a1 = *(const s16x8*)&Qs[(w*16 + lr)*KP + 32 + lq*8];
    f32x4 acc[16];
    #pragma unroll
    for (int fn = 0; fn < 16; ++fn) {
        s16x8 b0 = *(const s16x8*)&Ks[(fn*16 + lr)*KP + lq*8];
        s16x8 b1 = *(const s16x8*)&Ks[(fn*16 + lr)*KP + 32 + lq*8];
        f32x4 c = {0.f, 0.f, 0.f, 0.f};
        c = __builtin_amdgcn_mfma_f32_16x16x32_bf16(a0, b0, c, 0, 0, 0);
        c = __builtin_amdgcn_mfma_f32_16x16x32_bf16(a1, b1, c, 0, 0, 0);
        acc[fn] = c;
    }
    #pragma unroll
    for (int r = 0; r < 4; ++r) {
        float mx = -1e30f;
        #pragma unroll
        for (int fn = 0; fn < 16; ++fn) mx = fmaxf(mx, acc[fn][r]);
        #pragma unroll
        for (int off = 1; off < 16; off <<= 1) mx = fmaxf(mx, __shfl_xor(mx, off, 64));
        float e[16], sum = 0.f;
        #pragma unroll
        for (int fn = 0; fn < 16; ++fn) { e[fn] = __expf(acc[fn][r] - mx); sum += e[fn]; }
        #pragma unroll
        for (int off = 1; off < 16; off <<= 1) sum += __shfl_xor(sum, off, 64);
        float inv = 1.f / sum;
        long rowg = m0 + w*16 + lq*4 + r;
        #pragma unroll
        for (int fn = 0; fn < 16; ++fn)
            P[(long)bh*65536 + rowg*256 + fn*16 + lr] = f2bf(e[fn]*inv);
    }
}

// rms over 512 cols, f32 in -> bf16 out. 4 rows/block (1 per wave).
__global__ __launch_bounds__(256)
void rms_rows(const float* __restrict__ in, unsigned short* __restrict__ out)
{
    int row = blockIdx.x*4 + (threadIdx.x >> 6);
    int lane = threadIdx.x & 63;
    const float* r = in + (long)row*DIM_;
    float4 v0 = *(const float4*)&r[lane*4];
    float4 v1 = *(const float4*)&r[256 + lane*4];
    float ss = v0.x*v0.x + v0.y*v0.y + v0.z*v0.z + v0.w*v0.w
             + v1.x*v1.x + v1.y*v1.y + v1.z*v1.z + v1.w*v1.w;
    #pragma unroll
    for (int off = 1; off < 64; off <<= 1) ss += __shfl_xor(ss, off, 64);
    float sc = rsqrtf(ss * (1.f/512.f) + 1e-6f);
    ushort4 o0, o1;
    o0.x = f2bf(v0.x*sc); o0.y = f2bf(v0.y*sc); o0.z = f2bf(v0.z*sc); o0.w = f2bf(v0.w*sc);
    o1.x = f2bf(v1.x*sc); o1.y = f2bf(v1.y*sc); o1.z = f2bf(v1.z*sc); o1.w = f2bf(v1.w*sc);
    *(ushort4*)&out[(long)row*DIM_ + lane*4] = o0;
    *(ushort4*)&out[(long)row*DIM_ + 256 + lane*4] = o1;
}

// per-token QK rms-norm + rope (+1/8 score scale on Q), V transpose. grid 8192.
__global__ __launch_bounds__(256)
void qk_rope(const float* __restrict__ qkv, const float* __restrict__ cost,
             const float* __restrict__ sint, unsigned short* __restrict__ Qn,
             unsigned short* __restrict__ Kn, unsigned short* __restrict__ VT)
{
    int token = blockIdx.x;            // b*S + s
    int s = token & 255, b = token >> 8;
    int t = threadIdx.x;
    int hh = t >> 5, j = t & 31;
    const float* row = qkv + (long)token*1536;
    float q0 = row[hh*64 + 2*j],        q1 = row[hh*64 + 2*j + 1];
    float k0 = row[512 + hh*64 + 2*j],  k1 = row[512 + hh*64 + 2*j + 1];
    float qs = q0*q0 + q1*q1, ks = k0*k0 + k1*k1;
    #pragma unroll
    for (int off = 1; off < 32; off <<= 1) { qs += __shfl_xor(qs, off, 64); ks += __shfl_xor(ks, off, 64); }
    float qsc = rsqrtf(qs*(1.f/64.f) + 1e-6f) * 0.125f;
    float ksc = rsqrtf(ks*(1.f/64.f) + 1e-6f);
    float c = cost[s*32 + j], sn = sint[s*32 + j];
    q0 *= qsc; q1 *= qsc; k0 *= ksc; k1 *= ksc;
    float qo0 = q0*c - q1*sn, qo1 = q0*sn + q1*c;
    float ko0 = k0*c - k1*sn, ko1 = k0*sn + k1*c;
    int bh = b*HEADS_ + hh;
    long base = (long)bh*S_*HD_ + (long)s*HD_ + 2*j;
    ushort2 qw; qw.x = f2bf(qo0); qw.y = f2bf(qo1);
    ushort2 kw; kw.x = f2bf(ko0); kw.y = f2bf(ko1);
    *(ushort2*)&Qn[base] = qw;
    *(ushort2*)&Kn[base] = kw;
    float v0 = row[1024 + hh*64 + 2*j], v1 = row[1024 + hh*64 + 2*j + 1];
    VT[(long)bh*S_*HD_ + (long)(2*j)*S_ + s]     = f2bf(v0);
    VT[(long)bh*S_*HD_ + (long)(2*j+1)*S_ + s]   = f2bf(v1);
}

// h[b,d,:] = mask ? embed_W[:, idx] : 0  (+ pos_embed[d,:]).  grid 8192.
__global__ __launch_bounds__(256)
void embed_k(float* __restrict__ h, const int* __restrict__ xidx,
             const float* __restrict__ eW, const float* __restrict__ pos, int par)
{
    int row = blockIdx.x;
    int d = row & 255;
    int mask = (((d & 1) == 0) == (par != 0)) ? 1 : 0;
    int idx = xidx[row];
    int t = threadIdx.x;
    #pragma unroll
    for (int c0 = 0; c0 < 2; ++c0) {
        int c = c0*256 + t;
        float v = pos[d*DIM_ + c];
        if (mask) v += eW[(long)c*K_ + idx];
        h[(long)row*DIM_ + c] = v;
    }
}

__global__ __launch_bounds__(256)
void skip_scale(float* __restrict__ h, const float* __restrict__ alpha, int n4)
{
    float s = 1.f + 1.f/(1.f + __expf(-alpha[0]));
    for (long i = blockIdx.x*256 + threadIdx.x; i < n4; i += (long)gridDim.x*256) {
        float4 v = ((float4*)h)[i];
        v.x *= s; v.y *= s; v.z *= s; v.w *= s;
        ((float4*)h)[i] = v;
    }
}

__global__ __launch_bounds__(256)
void skip_add(float* __restrict__ h, const float* __restrict__ skip,
              const float* __restrict__ alpha, int n4)
{
    float s = 1.f/(1.f + __expf(-alpha[0]));
    for (long i = blockIdx.x*256 + threadIdx.x; i < n4; i += (long)gridDim.x*256) {
        float4 v = ((float4*)h)[i];
        float4 u = ((const float4*)skip)[i];
        v.x += s*u.x; v.y += s*u.y; v.z += s*u.z; v.w += s*u.w;
        ((float4*)h)[i] = v;
    }
}

// argmax over 128 logits; update x_idx where mask==0.  4 rows/block.
__global__ __launch_bounds__(256)
void argmax_update(const float* __restrict__ logits, int* __restrict__ xidx, int par)
{
    int row = blockIdx.x*4 + (threadIdx.x >> 6);
    int d = row & 255;
    int maskbit = (((d & 1) == 0) == (par != 0)) ? 1 : 0;
    if (maskbit) return;
    int lane = threadIdx.x & 63;
    float v0 = logits[(long)row*K_ + lane], v1 = logits[(long)row*K_ + 64 + lane];
    float bv; int bi;
    if (v1 > v0) { bv = v1; bi = lane + 64; } else { bv = v0; bi = lane; }
    #pragma unroll
    for (int off = 1; off < 64; off <<= 1) {
        float ov = __shfl_xor(bv, off, 64);
        int oi = __shfl_xor(bi, off, 64);
        if (ov > bv || (ov == bv && oi < bi)) { bv = ov; bi = oi; }
    }
    if (lane == 0) xidx[row] = (xidx[row] - bi) & (K_ - 1);
}

__global__ __launch_bounds__(256)
void setup_cossin(float* __restrict__ cost, float* __restrict__ sint)
{
    for (int idx = blockIdx.x*256 + threadIdx.x; idx < D_*32; idx += gridDim.x*256) {
        int d = idx >> 5, j = idx & 31;
        float inv = powf(10000.f, -(float)j/32.f);
        float ang = (float)d * inv;
        cost[idx] = cosf(ang);
        sint[idx] = sinf(ang);
    }
}

__global__ __launch_bounds__(256)
void setup_lse(const float* __restrict__ bl, float* __restrict__ lse)
{
    int row = blockIdx.x*4 + (threadIdx.x >> 6);
    int lane = threadIdx.x & 63;
    float v0 = bl[(long)row*K_ + lane], v1 = bl[(long)row*K_ + 64 + lane];
    float mx = fmaxf(v0, v1);
    #pragma unroll
    for (int off = 1; off < 64; off <<= 1) mx = fmaxf(mx, __shfl_xor(mx, off, 64));
    float s = __expf(v0 - mx) + __expf(v1 - mx);
    #pragma unroll
    for (int off = 1; off < 64; off <<= 1) s += __shfl_xor(s, off, 64);
    if (lane == 0) lse[row] = logf(s) + mx;
}

__global__ __launch_bounds__(256)
void init_xidx(const int* __restrict__ y, int* __restrict__ xidx)
{
    int i = blockIdx.x*256 + threadIdx.x;
    if (i < TOK_) xidx[i] = y[i];
}

__global__ __launch_bounds__(256)
void final_out(const float* __restrict__ bl, const float* __restrict__ lse,
               const int* __restrict__ xidx, float* __restrict__ out)
{
    int b = blockIdx.x;
    int d = threadIdx.x;            // D_ == 256 == blockDim
    float v = bl[(long)d*K_ + xidx[b*D_ + d]] - lse[d];
    #pragma unroll
    for (int off = 1; off < 64; off <<= 1) v += __shfl_xor(v, off, 64);
    __shared__ float wsum[4];
    if ((threadIdx.x & 63) == 0) wsum[threadIdx.x >> 6] = v;
    __syncthreads();
    if (threadIdx.x == 0) out[b] = wsum[0] + wsum[1] + wsum[2] + wsum[3];
}

// ---------------------------------------------------------------------------
extern "C" void kernel_launch(void* const* d_in, const int* in_sizes, int n_in,
                              void* d_out, int out_size, void* d_ws, size_t ws_size,
                              hipStream_t stream)
{
    const int*   y        = (const int*)  d_in[0];
    const float* base_lg  = (const float*)d_in[1];
    const float* embed_W  = (const float*)d_in[2];
    const float* pos_emb  = (const float*)d_in[3];
    const float* qkv_W    = (const float*)d_in[4];
    const float* out_W    = (const float*)d_in[5];
    const float* up_W     = (const float*)d_in[6];
    const float* down_W   = (const float*)d_in[7];
    const float* skip_al  = (const float*)d_in[8];
    const float* head_W   = (const float*)d_in[9];
    const float* head_b   = (const float*)d_in[10];
    float* out = (float*)d_out;

    char* w = (char*)d_ws;
    auto alloc = [&](size_t bytes) { char* p = w; w += (bytes + 255) & ~(size_t)255; return p; };
    float* cost   = (float*)alloc(D_*32*4);
    float* sint   = (float*)alloc(D_*32*4);
    float* lse    = (float*)alloc(D_*4);
    int*   xidx   = (int*)  alloc(TOK_*4);
    float* h      = (float*)alloc((size_t)TOK_*DIM_*4);
    float* skip   = (float*)alloc((size_t)TOK_*DIM_*4);
    unsigned short* xa = (unsigned short*)alloc((size_t)TOK_*DIM_*2);
    float* U      = (float*)alloc((size_t)TOK_*1536*4);          // qkv f32
    unsigned short* P  = (unsigned short*)alloc((size_t)256*S_*S_*2); // softmax P / up-out
    unsigned short* Qn = (unsigned short*)alloc((size_t)256*S_*HD_*2);
    unsigned short* Kn = (unsigned short*)alloc((size_t)256*S_*HD_*2);
    unsigned short* VT = (unsigned short*)alloc((size_t)256*S_*HD_*2);
    unsigned short* O  = (unsigned short*)alloc((size_t)TOK_*DIM_*2);
    float* logits = (float*)alloc((size_t)TOK_*K_*4);
    // per-flow bf16 weights
    unsigned short* wq = (unsigned short*)alloc((size_t)4*1536*512*2);
    unsigned short* wo = (unsigned short*)alloc((size_t)4*512*512*2);
    unsigned short* wu = (unsigned short*)alloc((size_t)4*2048*512*2);
    unsigned short* wd = (unsigned short*)alloc((size_t)4*512*2048*2);
    unsigned short* wh = (unsigned short*)alloc((size_t)K_*512*2);

    setup_cossin<<<32, 256, 0, stream>>>(cost, sint);
    setup_lse<<<D_/4, 256, 0, stream>>>(base_lg, lse);
    init_xidx<<<TOK_/256, 256, 0, stream>>>(y, xidx);

    const int n4 = TOK_*DIM_/4;

    for (int flow = 3; flow >= 0; --flow) {
        int par = (flow % 2 == 0) ? 1 : 0;

        // convert this flow's weights to bf16
        conv_bf16<<<1024, 256, 0, stream>>>(qkv_W + (long)flow*4*1536*512, wq, 4*1536*512/4);
        conv_bf16<<<1024, 256, 0, stream>>>(out_W + (long)flow*4*512*512,  wo, 4*512*512/4);
        conv_bf16<<<1024, 256, 0, stream>>>(up_W  + (long)flow*4*2048*512, wu, 4*2048*512/4);
        conv_bf16<<<1024, 256, 0, stream>>>(down_W+ (long)flow*4*512*2048, wd, 4*512*2048/4);
        conv_bf16<<<64, 256, 0, stream>>>(head_W + (long)flow*K_*512, wh, K_*512/4);

        embed_k<<<TOK_, 256, 0, stream>>>(h, xidx,
            embed_W + (long)flow*DIM_*K_, pos_emb + (long)flow*D_*DIM_, par);

        for (int layer = 0; layer < 4; ++layer) {
            const unsigned short* qkvW = wq + (long)layer*1536*512;
            const unsigned short* oW   = wo + (long)layer*512*512;
            const unsigned short* upW  = wu + (long)layer*2048*512;
            const unsigned short* dnW  = wd + (long)layer*512*2048;

            if (layer == 2) skip_scale<<<1024, 256, 0, stream>>>(h, skip_al + flow*2 + 0, n4);
            if (layer == 3) skip_add  <<<1024, 256, 0, stream>>>(h, skip, skip_al + flow*2 + 1, n4);

            // ---- attention ----
            rms_rows<<<TOK_/4, 256, 0, stream>>>(h, xa);
            gemm_lds<128,128,0,true><<<dim3(12,64,1), 256, 0, stream>>>(
                xa, qkvW, U, nullptr, 512, 1536, 0, 0, 1, 0, 0);
            qk_rope<<<TOK_, 256, 0, stream>>>(U, cost, sint, Qn, Kn, VT);
            attn_scores<<<dim3(4,256), 256, 0, stream>>>(Qn, Kn, P);
            gemm_lds<128,64,4,false><<<dim3(1,2,256), 256, 0, stream>>>(
                P, VT, O, nullptr, 256, 512, 65536, 16384, 8, (long)S_*DIM_, 64);
            gemm_lds<128,128,1,true><<<dim3(4,64,1), 256, 0, stream>>>(
                O, oW, h, nullptr, 512, 512, 0, 0, 1, 0, 0);

            // ---- mlp ----
            rms_rows<<<TOK_/4, 256, 0, stream>>>(h, xa);
            gemm_lds<128,128,2,true><<<dim3(16,64,1), 256, 0, stream>>>(
                xa, upW, P, nullptr, 512, 2048, 0, 0, 1, 0, 0);
            gemm_lds<128,128,1,true><<<dim3(4,64,1), 256, 0, stream>>>(
                P, dnW, h, nullptr, 2048, 512, 0, 0, 1, 0, 0);

            if (layer == 0)
                hipMemcpyAsync(skip, h, (size_t)TOK_*DIM_*4, hipMemcpyDeviceToDevice, stream);
        }

        rms_rows<<<TOK_/4, 256, 0, stream>>>(h, xa);
        gemm_lds<128,128,3,true><<<dim3(1,64,1), 256, 0, stream>>>(
            xa, wh, logits, head_b + flow*K_, 512, 128, 0, 0, 1, 0, 0);
        argmax_update<<<TOK_/4, 256, 0, stream>>>(logits, xidx, par);
    }

    final_out<<<B_, 256, 0, stream>>>(base_lg, lse, xidx, out);
}

// Round 4
// 3060.006 us; speedup vs baseline: 1.5575x; 1.2704x over previous
//
#include <hip/hip_runtime.h>

typedef __attribute__((ext_vector_type(8))) short s16x8;
typedef __attribute__((ext_vector_type(4))) float f32x4;

#define B_ 32
#define D_ 256
#define K_ 128
#define DIM_ 512
#define HEADS_ 8
#define HD_ 64
#define S_ 256
#define TOK_ (B_*D_)          // 8192 rows

__device__ __forceinline__ unsigned short f2bf(float f) {
    union { float f; unsigned int u; } v; v.f = f;
    unsigned int r = v.u + 0x7fffu + ((v.u >> 16) & 1u);
    return (unsigned short)(r >> 16);
}
__device__ __forceinline__ float bf2f(unsigned short u) {
    union { unsigned int u; float f; } v; v.u = ((unsigned int)u) << 16;
    return v.f;
}

typedef const __attribute__((address_space(1))) unsigned int* gp1_t;
typedef __attribute__((address_space(3))) unsigned int* lp3_t;
__device__ __forceinline__ void gload16(const void* g, void* l) {
    __builtin_amdgcn_global_load_lds((gp1_t)g, (lp3_t)l, 16, 0, 0);
}

// ---------------------------------------------------------------------------
// bf16 GEMM, 2-phase double-buffered global_load_lds staging, BK=32.
// Seg-swizzle: LDS pos (r,s) holds global (r, s ^ ((r>>1)&3))  [2-way banks]
// C[m][n] = sum_k A[m][k]*Bw[n][k];  A,Bw bf16 row-major (lda=ldb=K).
// EPI: 0 store f32; 1 f32 +=; 2 relu^2->bf16; 3 +bias->f32; 4 store bf16
// batch z: A += z*sA, B += z*sB, C += (z/zdiv)*sC1 + (z%zdiv)*sC2
// ---------------------------------------------------------------------------
template<int BM, int BN, int EPI, bool SWZ>
__global__ __launch_bounds__(256)
void gemm_p(const unsigned short* __restrict__ A, const unsigned short* __restrict__ Bw,
            void* __restrict__ Cv, const float* __restrict__ bias,
            int K, int ldc, long sA, long sB, int zdiv, long sC1, long sC2)
{
    constexpr int FM = BM/32, FN = BN/32;   // 4 waves: 2x2
    constexpr int AP = BM*4/256, BP = BN*4/256;
    __shared__ unsigned short As[2][BM*32];
    __shared__ unsigned short Bs[2][BN*32];

    const int tid = threadIdx.x;
    const int z = blockIdx.z;
    int bx = blockIdx.x, by = blockIdx.y;
    if constexpr (SWZ) {
        int gx = gridDim.x;
        int nwg = gx * gridDim.y;
        int flat = by*gx + bx;
        int cpx = nwg >> 3;
        int swz = (flat & 7)*cpx + (flat >> 3);
        by = swz / gx; bx = swz - by*gx;
    }
    const long m0 = (long)by * BM;
    const long n0 = (long)bx * BN;
    const unsigned short* Ab = A + z*sA + m0*K;
    const unsigned short* Bb = Bw + z*sB + n0*K;
    const long coff = (long)(z/zdiv)*sC1 + (long)(z%zdiv)*sC2;

    const int w = tid >> 6, lane = tid & 63;
    const int wm = w >> 1, wn = w & 1;
    const int lr = lane & 15, lq = lane >> 4;

    f32x4 acc[FM][FN] = {};

    auto stage = [&](int buf, int k0) {
        #pragma unroll
        for (int p = 0; p < AP; ++p) {
            int idx = p*256 + tid;
            int r = idx >> 2, s = idx & 3;
            int sp = s ^ ((r >> 1) & 3);
            gload16(&Ab[(long)r*K + k0 + sp*8], &As[buf][idx*8]);
        }
        #pragma unroll
        for (int p = 0; p < BP; ++p) {
            int idx = p*256 + tid;
            int r = idx >> 2, s = idx & 3;
            int sp = s ^ ((r >> 1) & 3);
            gload16(&Bb[(long)r*K + k0 + sp*8], &Bs[buf][idx*8]);
        }
    };

    stage(0, 0);
    __syncthreads();
    const int nk = K >> 5;
    for (int t = 0; t < nk; ++t) {
        int cur = t & 1;
        if (t + 1 < nk) stage(cur ^ 1, (t+1) << 5);
        s16x8 af[FM], bfr[FN];
        #pragma unroll
        for (int fm = 0; fm < FM; ++fm) {
            int row = wm*FM*16 + fm*16 + lr;
            af[fm] = *(const s16x8*)&As[cur][row*32 + (lq ^ ((row>>1)&3))*8];
        }
        #pragma unroll
        for (int fn = 0; fn < FN; ++fn) {
            int row = wn*FN*16 + fn*16 + lr;
            bfr[fn] = *(const s16x8*)&Bs[cur][row*32 + (lq ^ ((row>>1)&3))*8];
        }
        #pragma unroll
        for (int fm = 0; fm < FM; ++fm)
            #pragma unroll
            for (int fn = 0; fn < FN; ++fn)
                acc[fm][fn] = __builtin_amdgcn_mfma_f32_16x16x32_bf16(
                    af[fm], bfr[fn], acc[fm][fn], 0, 0, 0);
        __syncthreads();
    }

    #pragma unroll
    for (int fm = 0; fm < FM; ++fm) {
        long mrow = m0 + wm*FM*16 + fm*16 + lq*4;
        #pragma unroll
        for (int fn = 0; fn < FN; ++fn) {
            long ncol = n0 + wn*FN*16 + fn*16 + lr;
            #pragma unroll
            for (int r = 0; r < 4; ++r) {
                long ci = coff + (mrow + r)*ldc + ncol;
                float v = acc[fm][fn][r];
                if constexpr (EPI == 0) ((float*)Cv)[ci] = v;
                else if constexpr (EPI == 1) ((float*)Cv)[ci] += v;
                else if constexpr (EPI == 2) { float t2 = fmaxf(v, 0.f); ((unsigned short*)Cv)[ci] = f2bf(t2*t2); }
                else if constexpr (EPI == 3) ((float*)Cv)[ci] = v + bias[ncol];
                else ((unsigned short*)Cv)[ci] = f2bf(v);
            }
        }
    }
}

// f32 -> bf16 weight conversion (vectorized, grid-stride)
__global__ __launch_bounds__(256)
void conv_bf16(const float* __restrict__ in, unsigned short* __restrict__ out, int n4)
{
    for (int i = blockIdx.x*256 + threadIdx.x; i < n4; i += gridDim.x*256) {
        float4 v = ((const float4*)in)[i];
        ushort4 o; o.x = f2bf(v.x); o.y = f2bf(v.y); o.z = f2bf(v.z); o.w = f2bf(v.w);
        ((ushort4*)out)[i] = o;
    }
}

// ---------------------------------------------------------------------------
// Fused scores + row softmax.  grid (4 qtiles, 256 bh).  Writes P bf16.
// Q is pre-scaled by 1/8 in qk_rope.
// ---------------------------------------------------------------------------
__global__ __launch_bounds__(256)
void attn_scores(const unsigned short* __restrict__ Qn,
                 const unsigned short* __restrict__ Kn,
                 unsigned short* __restrict__ P)
{
    constexpr int KP = 72;
    __shared__ unsigned short Qs[64*KP];
    __shared__ unsigned short Ks[256*KP];
    const int tid = threadIdx.x;
    const int bh = blockIdx.y;
    const int m0 = blockIdx.x * 64;
    const unsigned short* Qb = Qn + (long)bh*S_*HD_ + (long)m0*HD_;
    const unsigned short* Kb = Kn + (long)bh*S_*HD_;

    #pragma unroll
    for (int c = 0; c < 2; ++c) { int lin = c*256 + tid; int row = lin>>3, ko = (lin&7)*8;
        *(int4*)&Qs[row*KP + ko] = *(const int4*)&Qb[row*64 + ko]; }
    #pragma unroll
    for (int c = 0; c < 8; ++c) { int lin = c*256 + tid; int row = lin>>3, ko = (lin&7)*8;
        *(int4*)&Ks[row*KP + ko] = *(const int4*)&Kb[row*64 + ko]; }
    __syncthreads();

    const int w = tid >> 6, lane = tid & 63, lr = lane & 15, lq = lane >> 4;
    s16x8 a0 = *(const s16x8*)&Qs[(w*16 + lr)*KP + lq*8];
    s16x8 a1 = *(const s16x8*)&Qs[(w*16 + lr)*KP + 32 + lq*8];
    f32x4 acc[16];
    #pragma unroll
    for (int fn = 0; fn < 16; ++fn) {
        s16x8 b0 = *(const s16x8*)&Ks[(fn*16 + lr)*KP + lq*8];
        s16x8 b1 = *(const s16x8*)&Ks[(fn*16 + lr)*KP + 32 + lq*8];
        f32x4 c = {0.f, 0.f, 0.f, 0.f};
        c = __builtin_amdgcn_mfma_f32_16x16x32_bf16(a0, b0, c, 0, 0, 0);
        c = __builtin_amdgcn_mfma_f32_16x16x32_bf16(a1, b1, c, 0, 0, 0);
        acc[fn] = c;
    }
    #pragma unroll
    for (int r = 0; r < 4; ++r) {
        float mx = -1e30f;
        #pragma unroll
        for (int fn = 0; fn < 16; ++fn) mx = fmaxf(mx, acc[fn][r]);
        #pragma unroll
        for (int off = 1; off < 16; off <<= 1) mx = fmaxf(mx, __shfl_xor(mx, off, 64));
        float e[16], sum = 0.f;
        #pragma unroll
        for (int fn = 0; fn < 16; ++fn) { e[fn] = __expf(acc[fn][r] - mx); sum += e[fn]; }
        #pragma unroll
        for (int off = 1; off < 16; off <<= 1) sum += __shfl_xor(sum, off, 64);
        float inv = 1.f / sum;
        long rowg = m0 + w*16 + lq*4 + r;
        #pragma unroll
        for (int fn = 0; fn < 16; ++fn)
            P[(long)bh*65536 + rowg*256 + fn*16 + lr] = f2bf(e[fn]*inv);
    }
}

// rms over 512 cols, f32 in -> bf16 out. 4 rows/block (1 per wave).
__global__ __launch_bounds__(256)
void rms_rows(const float* __restrict__ in, unsigned short* __restrict__ out)
{
    int row = blockIdx.x*4 + (threadIdx.x >> 6);
    int lane = threadIdx.x & 63;
    const float* r = in + (long)row*DIM_;
    float4 v0 = *(const float4*)&r[lane*4];
    float4 v1 = *(const float4*)&r[256 + lane*4];
    float ss = v0.x*v0.x + v0.y*v0.y + v0.z*v0.z + v0.w*v0.w
             + v1.x*v1.x + v1.y*v1.y + v1.z*v1.z + v1.w*v1.w;
    #pragma unroll
    for (int off = 1; off < 64; off <<= 1) ss += __shfl_xor(ss, off, 64);
    float sc = rsqrtf(ss * (1.f/512.f) + 1e-6f);
    ushort4 o0, o1;
    o0.x = f2bf(v0.x*sc); o0.y = f2bf(v0.y*sc); o0.z = f2bf(v0.z*sc); o0.w = f2bf(v0.w*sc);
    o1.x = f2bf(v1.x*sc); o1.y = f2bf(v1.y*sc); o1.z = f2bf(v1.z*sc); o1.w = f2bf(v1.w*sc);
    *(ushort4*)&out[(long)row*DIM_ + lane*4] = o0;
    *(ushort4*)&out[(long)row*DIM_ + 256 + lane*4] = o1;
}

// per-token QK rms-norm + rope (+1/8 score scale on Q). bf16 in/out. grid 8192.
__global__ __launch_bounds__(256)
void qk_rope(const unsigned short* __restrict__ qkv, const float* __restrict__ cost,
             const float* __restrict__ sint, unsigned short* __restrict__ Qn,
             unsigned short* __restrict__ Kn)
{
    int token = blockIdx.x;            // b*S + s
    int s = token & 255;
    int t = threadIdx.x;
    int hh = t >> 5, j = t & 31;
    const unsigned short* row = qkv + (long)token*1536;
    ushort2 qu = *(const ushort2*)&row[hh*64 + 2*j];
    ushort2 ku = *(const ushort2*)&row[512 + hh*64 + 2*j];
    float q0 = bf2f(qu.x), q1 = bf2f(qu.y);
    float k0 = bf2f(ku.x), k1 = bf2f(ku.y);
    float qs = q0*q0 + q1*q1, ks = k0*k0 + k1*k1;
    #pragma unroll
    for (int off = 1; off < 32; off <<= 1) { qs += __shfl_xor(qs, off, 64); ks += __shfl_xor(ks, off, 64); }
    float qsc = rsqrtf(qs*(1.f/64.f) + 1e-6f) * 0.125f;
    float ksc = rsqrtf(ks*(1.f/64.f) + 1e-6f);
    float c = cost[s*32 + j], sn = sint[s*32 + j];
    q0 *= qsc; q1 *= qsc; k0 *= ksc; k1 *= ksc;
    float qo0 = q0*c - q1*sn, qo1 = q0*sn + q1*c;
    float ko0 = k0*c - k1*sn, ko1 = k0*sn + k1*c;
    int bh = (token >> 8)*HEADS_ + hh;
    long base = (long)bh*S_*HD_ + (long)s*HD_ + 2*j;
    ushort2 qw; qw.x = f2bf(qo0); qw.y = f2bf(qo1);
    ushort2 kw; kw.x = f2bf(ko0); kw.y = f2bf(ko1);
    *(ushort2*)&Qn[base] = qw;
    *(ushort2*)&Kn[base] = kw;
}

// V transpose: VT[bh][d][s] = U[b*256+s][1024 + h*64 + d].  grid (4 s-tiles, 256 bh).
__global__ __launch_bounds__(256)
void vtrans(const unsigned short* __restrict__ U, unsigned short* __restrict__ VT)
{
    __shared__ unsigned short t[64][65];
    int bh = blockIdx.y, s0 = blockIdx.x*64;
    int b = bh >> 3, h = bh & 7;
    int tid = threadIdx.x;
    #pragma unroll
    for (int p = 0; p < 2; ++p) {
        int lin = p*256 + tid;
        int sr = lin >> 3, dc = (lin & 7)*8;
        *(int4*)&t[sr][dc] = *(const int4*)&U[((long)(b*256 + s0 + sr))*1536 + 1024 + h*64 + dc];
    }
    __syncthreads();
    #pragma unroll
    for (int p = 0; p < 2; ++p) {
        int lin = p*256 + tid;
        int d = lin >> 3, sc = (lin & 7)*8;
        unsigned short tmp[8];
        #pragma unroll
        for (int i = 0; i < 8; ++i) tmp[i] = t[sc + i][d];
        *(int4*)&VT[(long)bh*16384 + (long)d*256 + s0 + sc] = *(const int4*)tmp;
    }
}

// h[b,d,:] = mask ? embed_W[:, idx] : 0  (+ pos_embed[d,:]).  grid 8192.
__global__ __launch_bounds__(256)
void embed_k(float* __restrict__ h, const int* __restrict__ xidx,
             const float* __restrict__ eW, const float* __restrict__ pos, int par)
{
    int row = blockIdx.x;
    int d = row & 255;
    int mask = (((d & 1) == 0) == (par != 0)) ? 1 : 0;
    int idx = xidx[row];
    int t = threadIdx.x;
    #pragma unroll
    for (int c0 = 0; c0 < 2; ++c0) {
        int c = c0*256 + t;
        float v = pos[d*DIM_ + c];
        if (mask) v += eW[(long)c*K_ + idx];
        h[(long)row*DIM_ + c] = v;
    }
}

__global__ __launch_bounds__(256)
void skip_scale(float* __restrict__ h, const float* __restrict__ alpha, int n4)
{
    float s = 1.f + 1.f/(1.f + __expf(-alpha[0]));
    for (long i = blockIdx.x*256 + threadIdx.x; i < n4; i += (long)gridDim.x*256) {
        float4 v = ((float4*)h)[i];
        v.x *= s; v.y *= s; v.z *= s; v.w *= s;
        ((float4*)h)[i] = v;
    }
}

__global__ __launch_bounds__(256)
void skip_add(float* __restrict__ h, const float* __restrict__ skip,
              const float* __restrict__ alpha, int n4)
{
    float s = 1.f/(1.f + __expf(-alpha[0]));
    for (long i = blockIdx.x*256 + threadIdx.x; i < n4; i += (long)gridDim.x*256) {
        float4 v = ((float4*)h)[i];
        float4 u = ((const float4*)skip)[i];
        v.x += s*u.x; v.y += s*u.y; v.z += s*u.z; v.w += s*u.w;
        ((float4*)h)[i] = v;
    }
}

// argmax over 128 logits; update x_idx where mask==0.  4 rows/block.
__global__ __launch_bounds__(256)
void argmax_update(const float* __restrict__ logits, int* __restrict__ xidx, int par)
{
    int row = blockIdx.x*4 + (threadIdx.x >> 6);
    int d = row & 255;
    int maskbit = (((d & 1) == 0) == (par != 0)) ? 1 : 0;
    if (maskbit) return;
    int lane = threadIdx.x & 63;
    float v0 = logits[(long)row*K_ + lane], v1 = logits[(long)row*K_ + 64 + lane];
    float bv; int bi;
    if (v1 > v0) { bv = v1; bi = lane + 64; } else { bv = v0; bi = lane; }
    #pragma unroll
    for (int off = 1; off < 64; off <<= 1) {
        float ov = __shfl_xor(bv, off, 64);
        int oi = __shfl_xor(bi, off, 64);
        if (ov > bv || (ov == bv && oi < bi)) { bv = ov; bi = oi; }
    }
    if (lane == 0) xidx[row] = (xidx[row] - bi) & (K_ - 1);
}

__global__ __launch_bounds__(256)
void setup_cossin(float* __restrict__ cost, float* __restrict__ sint)
{
    for (int idx = blockIdx.x*256 + threadIdx.x; idx < D_*32; idx += gridDim.x*256) {
        int d = idx >> 5, j = idx & 31;
        float inv = powf(10000.f, -(float)j/32.f);
        float ang = (float)d * inv;
        cost[idx] = cosf(ang);
        sint[idx] = sinf(ang);
    }
}

__global__ __launch_bounds__(256)
void setup_lse(const float* __restrict__ bl, float* __restrict__ lse)
{
    int row = blockIdx.x*4 + (threadIdx.x >> 6);
    int lane = threadIdx.x & 63;
    float v0 = bl[(long)row*K_ + lane], v1 = bl[(long)row*K_ + 64 + lane];
    float mx = fmaxf(v0, v1);
    #pragma unroll
    for (int off = 1; off < 64; off <<= 1) mx = fmaxf(mx, __shfl_xor(mx, off, 64));
    float s = __expf(v0 - mx) + __expf(v1 - mx);
    #pragma unroll
    for (int off = 1; off < 64; off <<= 1) s += __shfl_xor(s, off, 64);
    if (lane == 0) lse[row] = logf(s) + mx;
}

__global__ __launch_bounds__(256)
void init_xidx(const int* __restrict__ y, int* __restrict__ xidx)
{
    int i = blockIdx.x*256 + threadIdx.x;
    if (i < TOK_) xidx[i] = y[i];
}

__global__ __launch_bounds__(256)
void final_out(const float* __restrict__ bl, const float* __restrict__ lse,
               const int* __restrict__ xidx, float* __restrict__ out)
{
    int b = blockIdx.x;
    int d = threadIdx.x;            // D_ == 256 == blockDim
    float v = bl[(long)d*K_ + xidx[b*D_ + d]] - lse[d];
    #pragma unroll
    for (int off = 1; off < 64; off <<= 1) v += __shfl_xor(v, off, 64);
    __shared__ float wsum[4];
    if ((threadIdx.x & 63) == 0) wsum[threadIdx.x >> 6] = v;
    __syncthreads();
    if (threadIdx.x == 0) out[b] = wsum[0] + wsum[1] + wsum[2] + wsum[3];
}

// ---------------------------------------------------------------------------
extern "C" void kernel_launch(void* const* d_in, const int* in_sizes, int n_in,
                              void* d_out, int out_size, void* d_ws, size_t ws_size,
                              hipStream_t stream)
{
    const int*   y        = (const int*)  d_in[0];
    const float* base_lg  = (const float*)d_in[1];
    const float* embed_W  = (const float*)d_in[2];
    const float* pos_emb  = (const float*)d_in[3];
    const float* qkv_W    = (const float*)d_in[4];
    const float* out_W    = (const float*)d_in[5];
    const float* up_W     = (const float*)d_in[6];
    const float* down_W   = (const float*)d_in[7];
    const float* skip_al  = (const float*)d_in[8];
    const float* head_W   = (const float*)d_in[9];
    const float* head_b   = (const float*)d_in[10];
    float* out = (float*)d_out;

    char* w = (char*)d_ws;
    auto alloc = [&](size_t bytes) { char* p = w; w += (bytes + 255) & ~(size_t)255; return p; };
    float* cost   = (float*)alloc(D_*32*4);
    float* sint   = (float*)alloc(D_*32*4);
    float* lse    = (float*)alloc(D_*4);
    int*   xidx   = (int*)  alloc(TOK_*4);
    float* h      = (float*)alloc((size_t)TOK_*DIM_*4);
    float* skip   = (float*)alloc((size_t)TOK_*DIM_*4);
    unsigned short* xa = (unsigned short*)alloc((size_t)TOK_*DIM_*2);
    unsigned short* U  = (unsigned short*)alloc((size_t)TOK_*1536*2);     // qkv bf16
    unsigned short* P  = (unsigned short*)alloc((size_t)256*S_*S_*2);     // softmax P / up-out
    unsigned short* Qn = (unsigned short*)alloc((size_t)256*S_*HD_*2);
    unsigned short* Kn = (unsigned short*)alloc((size_t)256*S_*HD_*2);
    unsigned short* VT = (unsigned short*)alloc((size_t)256*S_*HD_*2);
    unsigned short* O  = (unsigned short*)alloc((size_t)TOK_*DIM_*2);
    float* logits = (float*)alloc((size_t)TOK_*K_*4);
    // per-flow bf16 weights
    unsigned short* wq = (unsigned short*)alloc((size_t)4*1536*512*2);
    unsigned short* wo = (unsigned short*)alloc((size_t)4*512*512*2);
    unsigned short* wu = (unsigned short*)alloc((size_t)4*2048*512*2);
    unsigned short* wd = (unsigned short*)alloc((size_t)4*512*2048*2);
    unsigned short* wh = (unsigned short*)alloc((size_t)K_*512*2);

    setup_cossin<<<32, 256, 0, stream>>>(cost, sint);
    setup_lse<<<D_/4, 256, 0, stream>>>(base_lg, lse);
    init_xidx<<<TOK_/256, 256, 0, stream>>>(y, xidx);

    const int n4 = TOK_*DIM_/4;

    for (int flow = 3; flow >= 0; --flow) {
        int par = (flow % 2 == 0) ? 1 : 0;

        // convert this flow's weights to bf16
        conv_bf16<<<1024, 256, 0, stream>>>(qkv_W + (long)flow*4*1536*512, wq, 4*1536*512/4);
        conv_bf16<<<1024, 256, 0, stream>>>(out_W + (long)flow*4*512*512,  wo, 4*512*512/4);
        conv_bf16<<<1024, 256, 0, stream>>>(up_W  + (long)flow*4*2048*512, wu, 4*2048*512/4);
        conv_bf16<<<1024, 256, 0, stream>>>(down_W+ (long)flow*4*512*2048, wd, 4*512*2048/4);
        conv_bf16<<<64, 256, 0, stream>>>(head_W + (long)flow*K_*512, wh, K_*512/4);

        embed_k<<<TOK_, 256, 0, stream>>>(h, xidx,
            embed_W + (long)flow*DIM_*K_, pos_emb + (long)flow*D_*DIM_, par);

        for (int layer = 0; layer < 4; ++layer) {
            const unsigned short* qkvW = wq + (long)layer*1536*512;
            const unsigned short* oW   = wo + (long)layer*512*512;
            const unsigned short* upW  = wu + (long)layer*2048*512;
            const unsigned short* dnW  = wd + (long)layer*512*2048;

            if (layer == 2) skip_scale<<<1024, 256, 0, stream>>>(h, skip_al + flow*2 + 0, n4);
            if (layer == 3) skip_add  <<<1024, 256, 0, stream>>>(h, skip, skip_al + flow*2 + 1, n4);

            // ---- attention ----
            rms_rows<<<TOK_/4, 256, 0, stream>>>(h, xa);
            gemm_p<128,128,4,true><<<dim3(12,64,1), 256, 0, stream>>>(
                xa, qkvW, U, nullptr, 512, 1536, 0, 0, 1, 0, 0);
            qk_rope<<<TOK_, 256, 0, stream>>>(U, cost, sint, Qn, Kn);
            vtrans<<<dim3(4,256), 256, 0, stream>>>(U, VT);
            attn_scores<<<dim3(4,256), 256, 0, stream>>>(Qn, Kn, P);
            gemm_p<128,64,4,false><<<dim3(1,2,256), 256, 0, stream>>>(
                P, VT, O, nullptr, 256, 512, 65536, 16384, 8, (long)S_*DIM_, 64);
            gemm_p<128,64,1,true><<<dim3(8,64,1), 256, 0, stream>>>(
                O, oW, h, nullptr, 512, 512, 0, 0, 1, 0, 0);

            // ---- mlp ----
            rms_rows<<<TOK_/4, 256, 0, stream>>>(h, xa);
            gemm_p<128,128,2,true><<<dim3(16,64,1), 256, 0, stream>>>(
                xa, upW, P, nullptr, 512, 2048, 0, 0, 1, 0, 0);
            gemm_p<128,64,1,true><<<dim3(8,64,1), 256, 0, stream>>>(
                P, dnW, h, nullptr, 2048, 512, 0, 0, 1, 0, 0);

            if (layer == 0)
                hipMemcpyAsync(skip, h, (size_t)TOK_*DIM_*4, hipMemcpyDeviceToDevice, stream);
        }

        rms_rows<<<TOK_/4, 256, 0, stream>>>(h, xa);
        gemm_p<64,64,3,true><<<dim3(2,128,1), 256, 0, stream>>>(
            xa, wh, logits, head_b + flow*K_, 512, 128, 0, 0, 1, 0, 0);
        argmax_update<<<TOK_/4, 256, 0, stream>>>(logits, xidx, par);
    }

    final_out<<<B_, 256, 0, stream>>>(base_lg, lse, xidx, out);
}

// Round 5
// 2858.957 us; speedup vs baseline: 1.6670x; 1.0703x over previous
//
#include <hip/hip_runtime.h>

typedef __attribute__((ext_vector_type(8))) short s16x8;
typedef __attribute__((ext_vector_type(4))) float f32x4;

#define B_ 32
#define D_ 256
#define K_ 128
#define DIM_ 512
#define HEADS_ 8
#define HD_ 64
#define S_ 256
#define TOK_ (B_*D_)          // 8192 rows

__device__ __forceinline__ unsigned short f2bf(float f) {
    union { float f; unsigned int u; } v; v.f = f;
    unsigned int r = v.u + 0x7fffu + ((v.u >> 16) & 1u);
    return (unsigned short)(r >> 16);
}
__device__ __forceinline__ float bf2f(unsigned short u) {
    union { unsigned int u; float f; } v; v.u = ((unsigned int)u) << 16;
    return v.f;
}

typedef const __attribute__((address_space(1))) unsigned int* gp1_t;
typedef __attribute__((address_space(3))) unsigned int* lp3_t;
__device__ __forceinline__ void gload16(const void* g, void* l) {
    __builtin_amdgcn_global_load_lds((gp1_t)g, (lp3_t)l, 16, 0, 0);
}

// ---------------------------------------------------------------------------
// bf16 GEMM, 2-phase double-buffered global_load_lds staging, BK=32.
// Seg-swizzle: LDS pos (r,s) holds global (r, s ^ ((r>>1)&3))
// C[m][n] = sum_k A[m][k]*Bw[n][k];  A,Bw bf16 row-major (lda=ldb=K).
// EPI: 2 relu^2->bf16; 3 +bias->f32; 4 store bf16; 5 bf16 +=
// ---------------------------------------------------------------------------
template<int BM, int BN, int EPI, bool SWZ>
__global__ __launch_bounds__(256)
void gemm_p(const unsigned short* __restrict__ A, const unsigned short* __restrict__ Bw,
            void* __restrict__ Cv, const float* __restrict__ bias,
            int K, int ldc)
{
    constexpr int FM = BM/32, FN = BN/32;   // 4 waves: 2x2
    constexpr int AP = BM*4/256, BP = BN*4/256;
    __shared__ unsigned short As[2][BM*32];
    __shared__ unsigned short Bs[2][BN*32];

    const int tid = threadIdx.x;
    int bx = blockIdx.x, by = blockIdx.y;
    if constexpr (SWZ) {
        int gx = gridDim.x;
        int nwg = gx * gridDim.y;
        int flat = by*gx + bx;
        int cpx = nwg >> 3;
        int swz = (flat & 7)*cpx + (flat >> 3);
        by = swz / gx; bx = swz - by*gx;
    }
    const long m0 = (long)by * BM;
    const long n0 = (long)bx * BN;
    const unsigned short* Ab = A + m0*K;
    const unsigned short* Bb = Bw + n0*K;

    const int w = tid >> 6, lane = tid & 63;
    const int wm = w >> 1, wn = w & 1;
    const int lr = lane & 15, lq = lane >> 4;

    f32x4 acc[FM][FN] = {};

    auto stage = [&](int buf, int k0) {
        #pragma unroll
        for (int p = 0; p < AP; ++p) {
            int idx = p*256 + tid;
            int r = idx >> 2, s = idx & 3;
            int sp = s ^ ((r >> 1) & 3);
            gload16(&Ab[(long)r*K + k0 + sp*8], &As[buf][idx*8]);
        }
        #pragma unroll
        for (int p = 0; p < BP; ++p) {
            int idx = p*256 + tid;
            int r = idx >> 2, s = idx & 3;
            int sp = s ^ ((r >> 1) & 3);
            gload16(&Bb[(long)r*K + k0 + sp*8], &Bs[buf][idx*8]);
        }
    };

    stage(0, 0);
    __syncthreads();
    const int nk = K >> 5;
    for (int t = 0; t < nk; ++t) {
        int cur = t & 1;
        if (t + 1 < nk) stage(cur ^ 1, (t+1) << 5);
        s16x8 af[FM], bfr[FN];
        #pragma unroll
        for (int fm = 0; fm < FM; ++fm) {
            int row = wm*FM*16 + fm*16 + lr;
            af[fm] = *(const s16x8*)&As[cur][row*32 + (lq ^ ((row>>1)&3))*8];
        }
        #pragma unroll
        for (int fn = 0; fn < FN; ++fn) {
            int row = wn*FN*16 + fn*16 + lr;
            bfr[fn] = *(const s16x8*)&Bs[cur][row*32 + (lq ^ ((row>>1)&3))*8];
        }
        #pragma unroll
        for (int fm = 0; fm < FM; ++fm)
            #pragma unroll
            for (int fn = 0; fn < FN; ++fn)
                acc[fm][fn] = __builtin_amdgcn_mfma_f32_16x16x32_bf16(
                    af[fm], bfr[fn], acc[fm][fn], 0, 0, 0);
        __syncthreads();
    }

    #pragma unroll
    for (int fm = 0; fm < FM; ++fm) {
        long mrow = m0 + wm*FM*16 + fm*16 + lq*4;
        #pragma unroll
        for (int fn = 0; fn < FN; ++fn) {
            long ncol = n0 + wn*FN*16 + fn*16 + lr;
            #pragma unroll
            for (int r = 0; r < 4; ++r) {
                long ci = (mrow + r)*ldc + ncol;
                float v = acc[fm][fn][r];
                if constexpr (EPI == 2) { float t2 = fmaxf(v, 0.f); ((unsigned short*)Cv)[ci] = f2bf(t2*t2); }
                else if constexpr (EPI == 3) ((float*)Cv)[ci] = v + bias[ncol];
                else if constexpr (EPI == 4) ((unsigned short*)Cv)[ci] = f2bf(v);
                else { unsigned short* cp = (unsigned short*)Cv;
                       cp[ci] = f2bf(bf2f(cp[ci]) + v); }
            }
        }
    }
}

// f32 -> bf16 weight conversion
__global__ __launch_bounds__(256)
void conv_bf16(const float* __restrict__ in, unsigned short* __restrict__ out, int n4)
{
    for (int i = blockIdx.x*256 + threadIdx.x; i < n4; i += gridDim.x*256) {
        float4 v = ((const float4*)in)[i];
        ushort4 o; o.x = f2bf(v.x); o.y = f2bf(v.y); o.z = f2bf(v.z); o.w = f2bf(v.w);
        ((ushort4*)out)[i] = o;
    }
}

// ---------------------------------------------------------------------------
// Fused attention: scores + softmax + PV.  grid (4 qtiles, 256 bh).
// K staged in XOR-swizzled LDS [256][64]; P handoff in XOR-swizzled LDS
// [64][256]; Q and VT fragments read direct from global (L2-hot).
// Only ONE barrier (after K staging): each wave's PV reads only its own
// P rows.  Q pre-scaled by 1/8 in qk_rope.  Writes O bf16 [tok][512].
// ---------------------------------------------------------------------------
__global__ __launch_bounds__(256)
void attn_fused(const unsigned short* __restrict__ Qn,
                const unsigned short* __restrict__ Kn,
                const unsigned short* __restrict__ VT,
                unsigned short* __restrict__ O)
{
    __shared__ unsigned short Ks[256*64];   // 32 KB, 16B-granule XOR swizzle
    __shared__ unsigned short Ps[64*256];   // 32 KB, 16B-granule XOR swizzle
    const int tid = threadIdx.x;
    const int bh = blockIdx.y;
    const int m0 = blockIdx.x * 64;
    const unsigned short* Kb = Kn + (long)bh*S_*HD_;
    const unsigned short* Vb = VT + (long)bh*S_*HD_;

    // stage K: row kv, 8 granules of 16B; dest granule g^(row&7)
    #pragma unroll
    for (int c = 0; c < 8; ++c) {
        int lin = c*256 + tid;
        int row = lin >> 3, g = lin & 7;
        *(int4*)&Ks[row*64 + (g ^ (row & 7))*8] = *(const int4*)&Kb[row*64 + g*8];
    }

    const int w = tid >> 6, lane = tid & 63, lr = lane & 15, lq = lane >> 4;
    // Q fragments direct from global (row = one q per lr)
    const unsigned short* Qb = Qn + (long)bh*S_*HD_ + (long)(m0 + w*16 + lr)*HD_;
    s16x8 a0 = *(const s16x8*)&Qb[lq*8];
    s16x8 a1 = *(const s16x8*)&Qb[32 + lq*8];
    __syncthreads();

    // scores: wave w owns q rows [w*16, w*16+16)
    f32x4 acc[16];
    #pragma unroll
    for (int fn = 0; fn < 16; ++fn) {
        int row = fn*16 + lr;
        s16x8 b0 = *(const s16x8*)&Ks[row*64 + (lq ^ (row & 7))*8];
        s16x8 b1 = *(const s16x8*)&Ks[row*64 + ((4 + lq) ^ (row & 7))*8];
        f32x4 c = {0.f, 0.f, 0.f, 0.f};
        c = __builtin_amdgcn_mfma_f32_16x16x32_bf16(a0, b0, c, 0, 0, 0);
        c = __builtin_amdgcn_mfma_f32_16x16x32_bf16(a1, b1, c, 0, 0, 0);
        acc[fn] = c;
    }

    // softmax per row (16-lane groups) + write P to swizzled LDS
    #pragma unroll
    for (int r = 0; r < 4; ++r) {
        float mx = -1e30f;
        #pragma unroll
        for (int fn = 0; fn < 16; ++fn) mx = fmaxf(mx, acc[fn][r]);
        #pragma unroll
        for (int off = 1; off < 16; off <<= 1) mx = fmaxf(mx, __shfl_xor(mx, off, 64));
        float e[16], sum = 0.f;
        #pragma unroll
        for (int fn = 0; fn < 16; ++fn) { e[fn] = __expf(acc[fn][r] - mx); sum += e[fn]; }
        #pragma unroll
        for (int off = 1; off < 16; off <<= 1) sum += __shfl_xor(sum, off, 64);
        float inv = 1.f / sum;
        int q = w*16 + lq*4 + r;           // local q row
        #pragma unroll
        for (int fn = 0; fn < 16; ++fn) {
            int col = fn*16 + lr;
            Ps[q*256 + ((col >> 3) ^ (q & 7))*8 + (col & 7)] = f2bf(e[fn]*inv);
        }
    }

    // PV: O[q][d] = sum_kv P[q][kv] * VT[d][kv]   (wave reads own P rows)
    f32x4 oacc[4] = {};
    const int q = w*16 + lr;
    #pragma unroll
    for (int ks = 0; ks < 8; ++ks) {
        s16x8 pa = *(const s16x8*)&Ps[q*256 + ((ks*4 + lq) ^ (q & 7))*8];
        #pragma unroll
        for (int fn = 0; fn < 4; ++fn) {
            s16x8 vb = *(const s16x8*)&Vb[(long)(fn*16 + lr)*256 + ks*32 + lq*8];
            oacc[fn] = __builtin_amdgcn_mfma_f32_16x16x32_bf16(pa, vb, oacc[fn], 0, 0, 0);
        }
    }

    // epilogue: C-layout col=lane&15 (d), row=(lane>>4)*4+r (q)
    int b = bh >> 3, hh = bh & 7;
    #pragma unroll
    for (int fn = 0; fn < 4; ++fn) {
        int d = fn*16 + lr;
        #pragma unroll
        for (int r = 0; r < 4; ++r) {
            int qg = m0 + w*16 + lq*4 + r;
            O[(long)(b*256 + qg)*DIM_ + hh*64 + d] = f2bf(oacc[fn][r]);
        }
    }
}

// rms over 512 cols, bf16 in -> bf16 out. 4 rows/block (1 per wave).
__global__ __launch_bounds__(256)
void rms_rows(const unsigned short* __restrict__ in, unsigned short* __restrict__ out)
{
    int row = blockIdx.x*4 + (threadIdx.x >> 6);
    int lane = threadIdx.x & 63;
    const unsigned short* r = in + (long)row*DIM_ + lane*8;
    s16x8 v = *(const s16x8*)r;
    float f[8], ss = 0.f;
    #pragma unroll
    for (int i = 0; i < 8; ++i) { f[i] = bf2f((unsigned short)v[i]); ss += f[i]*f[i]; }
    #pragma unroll
    for (int off = 1; off < 64; off <<= 1) ss += __shfl_xor(ss, off, 64);
    float sc = rsqrtf(ss * (1.f/512.f) + 1e-6f);
    unsigned short o[8];
    #pragma unroll
    for (int i = 0; i < 8; ++i) o[i] = f2bf(f[i]*sc);
    *(int4*)&out[(long)row*DIM_ + lane*8] = *(const int4*)o;
}

// per-token QK rms-norm + rope (+1/8 score scale on Q). bf16 in/out. grid 8192.
__global__ __launch_bounds__(256)
void qk_rope(const unsigned short* __restrict__ qkv, const float* __restrict__ cost,
             const float* __restrict__ sint, unsigned short* __restrict__ Qn,
             unsigned short* __restrict__ Kn)
{
    int token = blockIdx.x;            // b*S + s
    int s = token & 255;
    int t = threadIdx.x;
    int hh = t >> 5, j = t & 31;
    const unsigned short* row = qkv + (long)token*1536;
    ushort2 qu = *(const ushort2*)&row[hh*64 + 2*j];
    ushort2 ku = *(const ushort2*)&row[512 + hh*64 + 2*j];
    float q0 = bf2f(qu.x), q1 = bf2f(qu.y);
    float k0 = bf2f(ku.x), k1 = bf2f(ku.y);
    float qs = q0*q0 + q1*q1, ks = k0*k0 + k1*k1;
    #pragma unroll
    for (int off = 1; off < 32; off <<= 1) { qs += __shfl_xor(qs, off, 64); ks += __shfl_xor(ks, off, 64); }
    float qsc = rsqrtf(qs*(1.f/64.f) + 1e-6f) * 0.125f;
    float ksc = rsqrtf(ks*(1.f/64.f) + 1e-6f);
    float c = cost[s*32 + j], sn = sint[s*32 + j];
    q0 *= qsc; q1 *= qsc; k0 *= ksc; k1 *= ksc;
    float qo0 = q0*c - q1*sn, qo1 = q0*sn + q1*c;
    float ko0 = k0*c - k1*sn, ko1 = k0*sn + k1*c;
    int bh = (token >> 8)*HEADS_ + hh;
    long base = (long)bh*S_*HD_ + (long)s*HD_ + 2*j;
    ushort2 qw; qw.x = f2bf(qo0); qw.y = f2bf(qo1);
    ushort2 kw; kw.x = f2bf(ko0); kw.y = f2bf(ko1);
    *(ushort2*)&Qn[base] = qw;
    *(ushort2*)&Kn[base] = kw;
}

// V transpose: VT[bh][d][s] = U[b*256+s][1024 + h*64 + d].  grid (4 s-tiles, 256 bh).
__global__ __launch_bounds__(256)
void vtrans(const unsigned short* __restrict__ U, unsigned short* __restrict__ VT)
{
    __shared__ unsigned short t[64][65];
    int bh = blockIdx.y, s0 = blockIdx.x*64;
    int b = bh >> 3, h = bh & 7;
    int tid = threadIdx.x;
    #pragma unroll
    for (int p = 0; p < 2; ++p) {
        int lin = p*256 + tid;
        int sr = lin >> 3, dc = (lin & 7)*8;
        *(int4*)&t[sr][dc] = *(const int4*)&U[((long)(b*256 + s0 + sr))*1536 + 1024 + h*64 + dc];
    }
    __syncthreads();
    #pragma unroll
    for (int p = 0; p < 2; ++p) {
        int lin = p*256 + tid;
        int d = lin >> 3, sc = (lin & 7)*8;
        unsigned short tmp[8];
        #pragma unroll
        for (int i = 0; i < 8; ++i) tmp[i] = t[sc + i][d];
        *(int4*)&VT[(long)bh*16384 + (long)d*256 + s0 + sc] = *(const int4*)tmp;
    }
}

// h[b,d,:] = (mask ? embed_W[:, idx] : 0) + pos_embed[d,:].  bf16 out. grid 8192.
__global__ __launch_bounds__(256)
void embed_k(unsigned short* __restrict__ h, const int* __restrict__ xidx,
             const float* __restrict__ eW, const float* __restrict__ pos, int par)
{
    int row = blockIdx.x;
    int d = row & 255;
    int mask = (((d & 1) == 0) == (par != 0)) ? 1 : 0;
    int idx = xidx[row];
    int t = threadIdx.x;
    int c = t*2;
    float2 p = *(const float2*)&pos[d*DIM_ + c];
    if (mask) { p.x += eW[(long)c*K_ + idx]; p.y += eW[(long)(c+1)*K_ + idx]; }
    ushort2 o; o.x = f2bf(p.x); o.y = f2bf(p.y);
    *(ushort2*)&h[(long)row*DIM_ + c] = o;
}

__global__ __launch_bounds__(256)
void skip_scale(unsigned short* __restrict__ h, const float* __restrict__ alpha, int n8)
{
    float s = 1.f + 1.f/(1.f + __expf(-alpha[0]));
    for (int i = blockIdx.x*256 + threadIdx.x; i < n8; i += gridDim.x*256) {
        s16x8 v = ((s16x8*)h)[i];
        unsigned short o[8];
        #pragma unroll
        for (int j = 0; j < 8; ++j) o[j] = f2bf(bf2f((unsigned short)v[j]) * s);
        ((int4*)h)[i] = *(const int4*)o;
    }
}

__global__ __launch_bounds__(256)
void skip_add(unsigned short* __restrict__ h, const unsigned short* __restrict__ skip,
              const float* __restrict__ alpha, int n8)
{
    float s = 1.f/(1.f + __expf(-alpha[0]));
    for (int i = blockIdx.x*256 + threadIdx.x; i < n8; i += gridDim.x*256) {
        s16x8 v = ((s16x8*)h)[i];
        s16x8 u = ((const s16x8*)skip)[i];
        unsigned short o[8];
        #pragma unroll
        for (int j = 0; j < 8; ++j)
            o[j] = f2bf(bf2f((unsigned short)v[j]) + s*bf2f((unsigned short)u[j]));
        ((int4*)h)[i] = *(const int4*)o;
    }
}

// argmax over 128 logits; update x_idx where mask==0.  4 rows/block.
__global__ __launch_bounds__(256)
void argmax_update(const float* __restrict__ logits, int* __restrict__ xidx, int par)
{
    int row = blockIdx.x*4 + (threadIdx.x >> 6);
    int d = row & 255;
    int maskbit = (((d & 1) == 0) == (par != 0)) ? 1 : 0;
    if (maskbit) return;
    int lane = threadIdx.x & 63;
    float v0 = logits[(long)row*K_ + lane], v1 = logits[(long)row*K_ + 64 + lane];
    float bv; int bi;
    if (v1 > v0) { bv = v1; bi = lane + 64; } else { bv = v0; bi = lane; }
    #pragma unroll
    for (int off = 1; off < 64; off <<= 1) {
        float ov = __shfl_xor(bv, off, 64);
        int oi = __shfl_xor(bi, off, 64);
        if (ov > bv || (ov == bv && oi < bi)) { bv = ov; bi = oi; }
    }
    if (lane == 0) xidx[row] = (xidx[row] - bi) & (K_ - 1);
}

__global__ __launch_bounds__(256)
void setup_cossin(float* __restrict__ cost, float* __restrict__ sint)
{
    for (int idx = blockIdx.x*256 + threadIdx.x; idx < D_*32; idx += gridDim.x*256) {
        int d = idx >> 5, j = idx & 31;
        float inv = powf(10000.f, -(float)j/32.f);
        float ang = (float)d * inv;
        cost[idx] = cosf(ang);
        sint[idx] = sinf(ang);
    }
}

__global__ __launch_bounds__(256)
void setup_lse(const float* __restrict__ bl, float* __restrict__ lse)
{
    int row = blockIdx.x*4 + (threadIdx.x >> 6);
    int lane = threadIdx.x & 63;
    float v0 = bl[(long)row*K_ + lane], v1 = bl[(long)row*K_ + 64 + lane];
    float mx = fmaxf(v0, v1);
    #pragma unroll
    for (int off = 1; off < 64; off <<= 1) mx = fmaxf(mx, __shfl_xor(mx, off, 64));
    float s = __expf(v0 - mx) + __expf(v1 - mx);
    #pragma unroll
    for (int off = 1; off < 64; off <<= 1) s += __shfl_xor(s, off, 64);
    if (lane == 0) lse[row] = logf(s) + mx;
}

__global__ __launch_bounds__(256)
void init_xidx(const int* __restrict__ y, int* __restrict__ xidx)
{
    int i = blockIdx.x*256 + threadIdx.x;
    if (i < TOK_) xidx[i] = y[i];
}

__global__ __launch_bounds__(256)
void final_out(const float* __restrict__ bl, const float* __restrict__ lse,
               const int* __restrict__ xidx, float* __restrict__ out)
{
    int b = blockIdx.x;
    int d = threadIdx.x;            // D_ == 256 == blockDim
    float v = bl[(long)d*K_ + xidx[b*D_ + d]] - lse[d];
    #pragma unroll
    for (int off = 1; off < 64; off <<= 1) v += __shfl_xor(v, off, 64);
    __shared__ float wsum[4];
    if ((threadIdx.x & 63) == 0) wsum[threadIdx.x >> 6] = v;
    __syncthreads();
    if (threadIdx.x == 0) out[b] = wsum[0] + wsum[1] + wsum[2] + wsum[3];
}

// ---------------------------------------------------------------------------
extern "C" void kernel_launch(void* const* d_in, const int* in_sizes, int n_in,
                              void* d_out, int out_size, void* d_ws, size_t ws_size,
                              hipStream_t stream)
{
    const int*   y        = (const int*)  d_in[0];
    const float* base_lg  = (const float*)d_in[1];
    const float* embed_W  = (const float*)d_in[2];
    const float* pos_emb  = (const float*)d_in[3];
    const float* qkv_W    = (const float*)d_in[4];
    const float* out_W    = (const float*)d_in[5];
    const float* up_W     = (const float*)d_in[6];
    const float* down_W   = (const float*)d_in[7];
    const float* skip_al  = (const float*)d_in[8];
    const float* head_W   = (const float*)d_in[9];
    const float* head_b   = (const float*)d_in[10];
    float* out = (float*)d_out;

    char* w = (char*)d_ws;
    auto alloc = [&](size_t bytes) { char* p = w; w += (bytes + 255) & ~(size_t)255; return p; };
    float* cost   = (float*)alloc(D_*32*4);
    float* sint   = (float*)alloc(D_*32*4);
    float* lse    = (float*)alloc(D_*4);
    int*   xidx   = (int*)  alloc(TOK_*4);
    unsigned short* h    = (unsigned short*)alloc((size_t)TOK_*DIM_*2);
    unsigned short* skip = (unsigned short*)alloc((size_t)TOK_*DIM_*2);
    unsigned short* xa   = (unsigned short*)alloc((size_t)TOK_*DIM_*2);
    unsigned short* U    = (unsigned short*)alloc((size_t)TOK_*1536*2);   // qkv bf16
    unsigned short* P    = (unsigned short*)alloc((size_t)TOK_*2048*2);   // up-out
    unsigned short* Qn   = (unsigned short*)alloc((size_t)256*S_*HD_*2);
    unsigned short* Kn   = (unsigned short*)alloc((size_t)256*S_*HD_*2);
    unsigned short* VT   = (unsigned short*)alloc((size_t)256*S_*HD_*2);
    unsigned short* O    = (unsigned short*)alloc((size_t)TOK_*DIM_*2);
    float* logits = (float*)alloc((size_t)TOK_*K_*4);
    // per-flow bf16 weights
    unsigned short* wq = (unsigned short*)alloc((size_t)4*1536*512*2);
    unsigned short* wo = (unsigned short*)alloc((size_t)4*512*512*2);
    unsigned short* wu = (unsigned short*)alloc((size_t)4*2048*512*2);
    unsigned short* wd = (unsigned short*)alloc((size_t)4*512*2048*2);
    unsigned short* wh = (unsigned short*)alloc((size_t)K_*512*2);

    setup_cossin<<<32, 256, 0, stream>>>(cost, sint);
    setup_lse<<<D_/4, 256, 0, stream>>>(base_lg, lse);
    init_xidx<<<TOK_/256, 256, 0, stream>>>(y, xidx);

    const int n8 = TOK_*DIM_/8;

    for (int flow = 3; flow >= 0; --flow) {
        int par = (flow % 2 == 0) ? 1 : 0;

        // convert this flow's weights to bf16
        conv_bf16<<<1024, 256, 0, stream>>>(qkv_W + (long)flow*4*1536*512, wq, 4*1536*512/4);
        conv_bf16<<<1024, 256, 0, stream>>>(out_W + (long)flow*4*512*512,  wo, 4*512*512/4);
        conv_bf16<<<1024, 256, 0, stream>>>(up_W  + (long)flow*4*2048*512, wu, 4*2048*512/4);
        conv_bf16<<<1024, 256, 0, stream>>>(down_W+ (long)flow*4*512*2048, wd, 4*512*2048/4);
        conv_bf16<<<64, 256, 0, stream>>>(head_W + (long)flow*K_*512, wh, K_*512/4);

        embed_k<<<TOK_, 256, 0, stream>>>(h, xidx,
            embed_W + (long)flow*DIM_*K_, pos_emb + (long)flow*D_*DIM_, par);

        for (int layer = 0; layer < 4; ++layer) {
            const unsigned short* qkvW = wq + (long)layer*1536*512;
            const unsigned short* oW   = wo + (long)layer*512*512;
            const unsigned short* upW  = wu + (long)layer*2048*512;
            const unsigned short* dnW  = wd + (long)layer*512*2048;

            if (layer == 2) skip_scale<<<1024, 256, 0, stream>>>(h, skip_al + flow*2 + 0, n8);
            if (layer == 3) skip_add  <<<1024, 256, 0, stream>>>(h, skip, skip_al + flow*2 + 1, n8);

            // ---- attention ----
            rms_rows<<<TOK_/4, 256, 0, stream>>>(h, xa);
            gemm_p<64,128,4,true><<<dim3(12,128,1), 256, 0, stream>>>(
                xa, qkvW, U, nullptr, 512, 1536);
            qk_rope<<<TOK_, 256, 0, stream>>>(U, cost, sint, Qn, Kn);
            vtrans<<<dim3(4,256), 256, 0, stream>>>(U, VT);
            attn_fused<<<dim3(4,256), 256, 0, stream>>>(Qn, Kn, VT, O);
            gemm_p<64,64,5,true><<<dim3(8,128,1), 256, 0, stream>>>(
                O, oW, h, nullptr, 512, 512);

            // ---- mlp ----
            rms_rows<<<TOK_/4, 256, 0, stream>>>(h, xa);
            gemm_p<64,128,2,true><<<dim3(16,128,1), 256, 0, stream>>>(
                xa, upW, P, nullptr, 512, 2048);
            gemm_p<64,64,5,true><<<dim3(8,128,1), 256, 0, stream>>>(
                P, dnW, h, nullptr, 2048, 512);

            if (layer == 0)
                hipMemcpyAsync(skip, h, (size_t)TOK_*DIM_*2, hipMemcpyDeviceToDevice, stream);
        }

        rms_rows<<<TOK_/4, 256, 0, stream>>>(h, xa);
        gemm_p<64,64,3,true><<<dim3(2,128,1), 256, 0, stream>>>(
            xa, wh, logits, head_b + flow*K_, 512, 128);
        argmax_update<<<TOK_/4, 256, 0, stream>>>(logits, xidx, par);
    }

    final_out<<<B_, 256, 0, stream>>>(base_lg, lse, xidx, out);
}